// Round 13
// baseline (301.378 us; speedup 1.0000x reference)
//
#include <hip/hip_runtime.h>
#include <hip/hip_bf16.h>

#define E_CNT 160000
#define N_CNT 10000

#define INV_STEP   2.125f          /* 17/8 */
#define EMB_C      33.734292f      /* 1.14136 * e^2 * sqrt(16) */
#define INVS320    0.05590170f     /* 1/sqrt(320) */
#define INVS8      0.35355339f     /* 1/sqrt(8)   */
#define INV_SQRT3  0.57735027f
#define KSCALE     0.051031036f    /* 0.25 (w/sqrt16) * 1/sqrt(24) (fctp norm) */

/* ---- workspace layout (float-sized offsets) ---- */
#define OFF_FLAG   0          /* 16 floats reserved (int flag at [0]) */
#define OFF_EAF    400016     /* 640000 */
#define OFF_AMFF   1040016    /* 160000 */
#define OFF_WK1F   1200656    /* 256 */
#define OFF_WV1F   1200912    /* 256 */
#define OFF_P      1219600    /* 400000 */
#define OFF_EXPV   1619600    /* 160000 (dst-sorted order) */
#define OFF_VBUF   1779600    /* 6400000 (dst-sorted order) */
#define OFF_DEG    8179600    /* 10000 ints (dst); reused as Z (zeroed at end of scan) */
#define OFF_Z      8179600    /* alias of OFF_DEG */
#define OFF_DEG2   8189600    /* 10000 ints (src) -- adjacent to DEG: single memset */
#define OFF_START  8199600    /* 10001 ints */
#define OFF_START2 8209601    /* 10001 ints */
#define OFF_CURS   8219602    /* 10000 ints */
#define OFF_CURS2  8229602    /* 10000 ints */
#define OFF_DPOS   8239602    /* 160000 ints: dst-position of edge at src-sorted slot */
#define OFF_ELIST2 8399602    /* 160000 ints */
#define OFF_G      8559632    /* 30,720,000 bf16 = 15,360,000 float slots (16B aligned) */
/* total 23,919,632 floats = 95.7 MB (same extent as R5-R12 -- verified mapped) */

static __device__ __forceinline__ float bf2f(__hip_bfloat16 b) { return __bfloat162float(b); }
static __device__ __forceinline__ float cvt(float v) { return v; }
static __device__ __forceinline__ float cvt(__hip_bfloat16 v) { return bf2f(v); }
static __device__ __forceinline__ float sanitize(float v) {
    return fminf(fmaxf(v, -1e30f), 1e30f);
}
static __device__ __forceinline__ unsigned short f2bf(float f) {
    unsigned x = __float_as_uint(f);
    unsigned r = (x + 0x7fffu + ((x >> 16) & 1u)) >> 16;   /* RN-even */
    return (unsigned short)r;
}
static __device__ __forceinline__ float bflo(unsigned u) { return __uint_as_float(u << 16); }
static __device__ __forceinline__ float bfhi(unsigned u) { return __uint_as_float(u & 0xffff0000u); }

/* load 4 consecutive floats from a maybe-bf16 / maybe-f32 buffer at element quad index i4 */
static __device__ __forceinline__ float4 load4(const void* p, int i4, int f32)
{
    if (f32) return ((const float4*)p)[i4];
    uint2 u = ((const uint2*)p)[i4];
    float4 r;
    r.x = bflo(u.x); r.y = bfhi(u.x);
    r.z = bflo(u.y); r.w = bfhi(u.y);
    return r;
}

/* 8-wide vector load: bf16 = one uint4 (16 B), f32 = two float4. p must be 16B-aligned. */
static __device__ __forceinline__ void ld8(const float* p, float (&r)[8])
{
    float4 a = ((const float4*)p)[0];
    float4 b = ((const float4*)p)[1];
    r[0] = a.x; r[1] = a.y; r[2] = a.z; r[3] = a.w;
    r[4] = b.x; r[5] = b.y; r[6] = b.z; r[7] = b.w;
}
static __device__ __forceinline__ void ld8(const __hip_bfloat16* p, float (&r)[8])
{
    uint4 u = *(const uint4*)p;
    r[0] = bflo(u.x); r[1] = bfhi(u.x); r[2] = bflo(u.y); r[3] = bfhi(u.y);
    r[4] = bflo(u.z); r[5] = bfhi(u.z); r[6] = bflo(u.w); r[7] = bfhi(u.w);
}

// ---------------- G builder: vectorized loads (R12 post-mortem: scalar-load issue-bound) ----------------
// G row layout per (n,p,c): 96 bf16 = 48 u32 = 12 uint4:
// [0..15] G1[w], [16..23] G2[w], [24+w*3+i] G3[w][i] (w<8), [48+w*3+i] G4[w][i] (1/sqrt3 folded)
template <typename T>
static __device__ __forceinline__ void build_G(
    const T* __restrict__ x, const T* __restrict__ W2b, int n, int p, int c, float* __restrict__ ws)
{
    float xs[40];
#pragma unroll
    for (int q = 0; q < 5; ++q) ld8(x + n * 40 + q * 8, *(float(*)[8])(xs + q * 8));
    const T* W2 = W2b + c * 576;

    float out[96];
#pragma unroll
    for (int k = 0; k < 96; ++k) out[k] = 0.f;

    /* seg1: W2[u*16+w], w=0..15 -> out[0..15] */
#pragma unroll
    for (int u = 0; u < 16; ++u) {
        float r0[8], r1[8];
        ld8(W2 + u * 16, r0);
        ld8(W2 + u * 16 + 8, r1);
        const float xv = xs[u];
#pragma unroll
        for (int w = 0; w < 8; ++w) {
            out[w]     = fmaf(r0[w], xv, out[w]);
            out[8 + w] = fmaf(r1[w], xv, out[8 + w]);
        }
    }
    /* seg2: W2[256+u*8+w] -> out[16..23] */
#pragma unroll
    for (int u = 0; u < 16; ++u) {
        float r[8];
        ld8(W2 + 256 + u * 8, r);
        const float xv = xs[u];
#pragma unroll
        for (int w = 0; w < 8; ++w) out[16 + w] = fmaf(r[w], xv, out[16 + w]);
    }
    /* seg3: W2[384+u*8+w] x1[u] -> out[24+w*3+i] */
#pragma unroll
    for (int u = 0; u < 8; ++u) {
        float r[8];
        ld8(W2 + 384 + u * 8, r);
        const float a0 = xs[16 + u * 3 + 0];
        const float a1 = xs[16 + u * 3 + 1];
        const float a2 = xs[16 + u * 3 + 2];
#pragma unroll
        for (int w = 0; w < 8; ++w) {
            out[24 + w * 3 + 0] = fmaf(r[w], a0, out[24 + w * 3 + 0]);
            out[24 + w * 3 + 1] = fmaf(r[w], a1, out[24 + w * 3 + 1]);
            out[24 + w * 3 + 2] = fmaf(r[w], a2, out[24 + w * 3 + 2]);
        }
    }
    /* seg4: W2[448+u*16+w] x1[u] -> out[48+w*3+i] (scaled by 1/sqrt3 below) */
#pragma unroll
    for (int u = 0; u < 8; ++u) {
        float r0[8], r1[8];
        ld8(W2 + 448 + u * 16, r0);
        ld8(W2 + 448 + u * 16 + 8, r1);
        const float a0 = xs[16 + u * 3 + 0];
        const float a1 = xs[16 + u * 3 + 1];
        const float a2 = xs[16 + u * 3 + 2];
#pragma unroll
        for (int w = 0; w < 8; ++w) {
            out[48 + w * 3 + 0] = fmaf(r0[w], a0, out[48 + w * 3 + 0]);
            out[48 + w * 3 + 1] = fmaf(r0[w], a1, out[48 + w * 3 + 1]);
            out[48 + w * 3 + 2] = fmaf(r0[w], a2, out[48 + w * 3 + 2]);
            out[48 + (8 + w) * 3 + 0] = fmaf(r1[w], a0, out[48 + (8 + w) * 3 + 0]);
            out[48 + (8 + w) * 3 + 1] = fmaf(r1[w], a1, out[48 + (8 + w) * 3 + 1]);
            out[48 + (8 + w) * 3 + 2] = fmaf(r1[w], a2, out[48 + (8 + w) * 3 + 2]);
        }
    }
#pragma unroll
    for (int k = 0; k < 48; ++k) out[48 + k] *= INV_SQRT3;

    uint4 ov[12];
    unsigned* ou = (unsigned*)ov;
#pragma unroll
    for (int k = 0; k < 48; ++k)
        ou[k] = (unsigned)f2bf(out[2 * k]) | ((unsigned)f2bf(out[2 * k + 1]) << 16);
    uint4* dp = (uint4*)((unsigned short*)(ws + OFF_G) + ((size_t)n * 2 + p) * 1536 + c * 96);
#pragma unroll
    for (int q = 0; q < 12; ++q) dp[q] = ov[q];
}

// ---------------- P builder (vectorized loads) ----------------
template <typename T>
static __device__ __forceinline__ void build_P(
    const T* __restrict__ x, const T* __restrict__ Wq0, const T* __restrict__ Wq1,
    const T* __restrict__ Wd0, const T* __restrict__ Wd1, int n, float* __restrict__ ws)
{
    float xs[40];
#pragma unroll
    for (int q = 0; q < 5; ++q) ld8(x + n * 40 + q * 8, *(float(*)[8])(xs + q * 8));

    float q0[16];
#pragma unroll
    for (int w = 0; w < 16; ++w) q0[w] = 0.f;
#pragma unroll
    for (int u = 0; u < 16; ++u) {
        float r0[8], r1[8];
        ld8(Wq0 + u * 16, r0);
        ld8(Wq0 + u * 16 + 8, r1);
        const float xv = xs[u];
#pragma unroll
        for (int w = 0; w < 8; ++w) {
            q0[w]     = fmaf(r0[w], xv, q0[w]);
            q0[8 + w] = fmaf(r1[w], xv, q0[8 + w]);
        }
    }
#pragma unroll
    for (int w = 0; w < 16; ++w) q0[w] *= 0.25f;

    float p0[16];
#pragma unroll
    for (int v = 0; v < 16; ++v) p0[v] = 0.f;
#pragma unroll
    for (int w = 0; w < 16; ++w) {
        float r0[8], r1[8];
        ld8(Wd0 + w * 16, r0);
        ld8(Wd0 + w * 16 + 8, r1);
        const float qv = q0[w];
#pragma unroll
        for (int v = 0; v < 8; ++v) {
            p0[v]     = fmaf(r0[v], qv, p0[v]);
            p0[8 + v] = fmaf(r1[v], qv, p0[8 + v]);
        }
    }
    float* pn = ws + OFF_P + n * 40;
#pragma unroll
    for (int v = 0; v < 16; ++v) pn[v] = sanitize(p0[v] * INVS320);

    float q1[24];
#pragma unroll
    for (int k = 0; k < 24; ++k) q1[k] = 0.f;
#pragma unroll
    for (int u = 0; u < 8; ++u) {
        float r[8];
        ld8(Wq1 + u * 8, r);
        const float a0 = xs[16 + u * 3 + 0];
        const float a1 = xs[16 + u * 3 + 1];
        const float a2 = xs[16 + u * 3 + 2];
#pragma unroll
        for (int w = 0; w < 8; ++w) {
            q1[w * 3 + 0] = fmaf(r[w], a0, q1[w * 3 + 0]);
            q1[w * 3 + 1] = fmaf(r[w], a1, q1[w * 3 + 1]);
            q1[w * 3 + 2] = fmaf(r[w], a2, q1[w * 3 + 2]);
        }
    }
#pragma unroll
    for (int k = 0; k < 24; ++k) q1[k] *= INVS8;

    float p1[24];
#pragma unroll
    for (int k = 0; k < 24; ++k) p1[k] = 0.f;
#pragma unroll
    for (int w = 0; w < 8; ++w) {
        float r[8];
        ld8(Wd1 + w * 8, r);
        const float b0 = q1[w * 3 + 0];
        const float b1 = q1[w * 3 + 1];
        const float b2 = q1[w * 3 + 2];
#pragma unroll
        for (int v = 0; v < 8; ++v) {
            p1[v * 3 + 0] = fmaf(r[v], b0, p1[v * 3 + 0]);
            p1[v * 3 + 1] = fmaf(r[v], b1, p1[v * 3 + 1]);
            p1[v * 3 + 2] = fmaf(r[v], b2, p1[v * 3 + 2]);
        }
    }
    const float sc = INVS320 * INV_SQRT3;
#pragma unroll
    for (int k = 0; k < 24; ++k) pn[16 + k] = sanitize(p1[k] * sc);
}

// ---------------- prepGP: [0,625) ingest+degrees | [625,1875) G | [1875,1915) P ----------------
__global__ __launch_bounds__(256) void prepgp_kernel(
    const void* __restrict__ x,   const void* __restrict__ ea,  const void* __restrict__ amf,
    const void* __restrict__ Wq0, const void* __restrict__ Wq1,
    const void* __restrict__ Wk1, const void* __restrict__ Wk2,
    const void* __restrict__ Wv1, const void* __restrict__ Wv2,
    const void* __restrict__ Wd0, const void* __restrict__ Wd1,
    const int* __restrict__ ei, float* __restrict__ ws)
{
    __shared__ int sflag;
    const int tid = threadIdx.x;
    const int blk = blockIdx.x;
    if (tid == 0) {
        const unsigned short* xb = (const unsigned short*)x;
        int cnt = 0;
        for (int k = 0; k < 256; k += 2) {
            unsigned e = (unsigned)((xb[k] >> 7) & 0xFF);
            if (e >= 141) ++cnt;
        }
        sflag = (cnt >= 8) ? 1 : 0;                  /* 1 = inputs are fp32 */
        if (blk == 0) *(int*)ws = sflag;
    }
    __syncthreads();
    const int f32 = sflag;

    if (blk < 625) {
        const int i = blk * 256 + tid;               /* < 160000 */
        if (i < 160000) ((float4*)(ws + OFF_EAF))[i] = load4(ea, i, f32);
        if (i < 40000) {
            ((float4*)(ws + OFF_AMFF))[i] = load4(amf, i, f32);
#pragma unroll
            for (int k = 0; k < 4; ++k) {
                atomicAdd((int*)(ws + OFF_DEG)  + ei[E_CNT + 4 * i + k], 1);   /* dst degree */
                atomicAdd((int*)(ws + OFF_DEG2) + ei[4 * i + k], 1);           /* src degree */
            }
        }
        if (i < 64) {
            ((float4*)(ws + OFF_WK1F))[i] = load4(Wk1, i, f32);
            ((float4*)(ws + OFF_WV1F))[i] = load4(Wv1, i, f32);
        }
        return;
    }
    if (blk < 1875) {
        const int t = (blk - 625) * 256 + tid;       /* < 320000 */
        const int p   = t / 160000;
        const int rem = t - p * 160000;
        const int c   = rem / 10000;
        const int n   = rem - c * 10000;
        const void* W2b = p ? Wv2 : Wk2;
        if (f32) build_G((const float*)x, (const float*)W2b, n, p, c, ws);
        else     build_G((const __hip_bfloat16*)x, (const __hip_bfloat16*)W2b, n, p, c, ws);
        return;
    }
    {
        const int n = (blk - 1875) * 256 + tid;
        if (n >= N_CNT) return;
        if (f32) build_P((const float*)x, (const float*)Wq0, (const float*)Wq1,
                         (const float*)Wd0, (const float*)Wd1, n, ws);
        else     build_P((const __hip_bfloat16*)x, (const __hip_bfloat16*)Wq0,
                         (const __hip_bfloat16*)Wq1, (const __hip_bfloat16*)Wd0,
                         (const __hip_bfloat16*)Wd1, n, ws);
    }
}

// ---------------- dual scan (512 threads: half dst, half src) + zero Z at end ----------------
__global__ __launch_bounds__(512) void scan_kernel(float* __restrict__ ws)
{
    __shared__ int ssum[512];
    const int t    = threadIdx.x;
    const int half = t >> 8;
    const int lt   = t & 255;
    int* deg   = (int*)(ws + (half ? OFF_DEG2   : OFF_DEG));
    int* start = (int*)(ws + (half ? OFF_START2 : OFF_START));
    int* curs  = (int*)(ws + (half ? OFF_CURS2  : OFF_CURS));
    const int base = lt * 40;
    int s = 0;
    for (int k = 0; k < 40; ++k) {
        int idx = base + k;
        if (idx < N_CNT) s += deg[idx];
    }
    ssum[t] = s;
    __syncthreads();
    for (int off = 1; off < 256; off <<= 1) {
        int v = (lt >= off) ? ssum[t - off] : 0;
        __syncthreads();
        ssum[t] += v;
        __syncthreads();
    }
    int run = ssum[t] - s;
    for (int k = 0; k < 40; ++k) {
        int idx = base + k;
        if (idx < N_CNT) {
            start[idx] = run;
            curs[idx]  = run;
            run += deg[idx];
        }
    }
    if (lt == 255) start[N_CNT] = E_CNT;
    __syncthreads();                                   /* all deg reads done */
    for (int k = t; k < N_CNT; k += 512) ws[OFF_Z + k] = 0.f;   /* Z aliases DEG */
}

// ---------------- fill: src-CSR + dst-position per src-slot ----------------
__global__ __launch_bounds__(256) void fill_kernel(const int* __restrict__ ei, float* __restrict__ ws)
{
    const int e = blockIdx.x * 256 + threadIdx.x;      /* 625*256 = 160000 exact */
    int pd = atomicAdd((int*)(ws + OFF_CURS)  + ei[E_CNT + e], 1);
    int ps = atomicAdd((int*)(ws + OFF_CURS2) + ei[e], 1);
    ((int*)(ws + OFF_ELIST2))[ps] = e;
    ((int*)(ws + OFF_DPOS))[ps]   = pd;
}

// ---------------- edge-kernel helpers ----------------
static __device__ __forceinline__ void load48(unsigned (&ub)[48], const uint4* __restrict__ rp)
{
#pragma unroll
    for (int q = 0; q < 12; ++q) {
        uint4 v = rp[q];
        ub[4 * q + 0] = v.x; ub[4 * q + 1] = v.y;
        ub[4 * q + 2] = v.z; ub[4 * q + 3] = v.w;
    }
}

/* consumption strictly in load (FIFO) order: k = 0..95 monotone */
static __device__ __forceinline__ void accum48(const unsigned (&ub)[48], float hc, float sh0,
    float s1x, float s1y, float s1z,
    float (&o0)[16], float (&o1)[24], float (&t2a)[8])
{
    const float hs = hc * sh0;
#define GVAL(k) (((k) & 1) ? bfhi(ub[(k) >> 1]) : bflo(ub[(k) >> 1]))
#pragma unroll
    for (int w = 0; w < 16; ++w) o0[w] = fmaf(hs, GVAL(w), o0[w]);
#pragma unroll
    for (int w = 0; w < 8; ++w) t2a[w] = fmaf(hc, GVAL(16 + w), t2a[w]);
#pragma unroll
    for (int k = 0; k < 24; ++k) o1[k] = fmaf(hs, GVAL(24 + k), o1[k]);
#pragma unroll
    for (int w = 0; w < 16; ++w) {
        float g = GVAL(48 + w * 3 + 0) * s1x;
        g = fmaf(GVAL(48 + w * 3 + 1), s1y, g);
        g = fmaf(GVAL(48 + w * 3 + 2), s1z, g);
        o0[w] = fmaf(hc, g, o0[w]);
    }
#undef GVAL
}

// ---------------- per-edge main kernel: R12 winner -- unchanged ----------------
__global__ __launch_bounds__(128, 2) void edge_kernel(
    const int* __restrict__ ei, float* __restrict__ ws)
{
    const int tid  = threadIdx.x;
    const int pass = tid >> 6;          /* wave 0: K, wave 1: V */
    const int lane = tid & 63;
    /* XCD swizzle: give each XCD a contiguous src range (2496 = 8*312) */
    const int b  = blockIdx.x;
    const int lb = (b < 2496) ? ((b & 7) * 312 + (b >> 3)) : b;
    const int sidx = lb * 64 + lane;    /* src-sorted edge index; 2500*64 = 160000 exact */
    const int e    = ((const int*)(ws + OFF_ELIST2))[sidx];
    const int dpos = ((const int*)(ws + OFF_DPOS))[sidx];
    const int src  = ei[e];
    const int dst  = ei[E_CNT + e];

    const uint4* Gp = (const uint4*)((const unsigned short*)(ws + OFF_G)
                                     + ((size_t)src * 2 + pass) * 1536);
    /* issue the first two G rows NOW -- everything below overlaps their latency */
    unsigned A[48], B[48];
    load48(A, Gp);
    load48(B, Gp + 12);

    const float d   = ws[OFF_AMFF + e];
    const float dsv = d * INV_STEP;
    float emb[16];
#pragma unroll
    for (int bb = 0; bb < 16; ++bb) {
        float t1 = dsv - (float)bb;
        float t2 = (float)(bb + 2) - dsv;
        float v = 0.f;
        if (t1 > 0.f && t2 > 0.f) v = EMB_C * expf(-1.f / t1 - 1.f / t2);
        emb[bb] = v;
    }

    const float* W1 = ws + (pass ? OFF_WV1F : OFF_WK1F);
    float h[16];
#pragma unroll
    for (int j = 0; j < 16; ++j) {
        float s = 0.f;
#pragma unroll
        for (int bb = 0; bb < 16; ++bb) s = fmaf(emb[bb], W1[bb * 16 + j], s);
        s *= 0.25f;
        h[j] = s / (1.f + expf(-s));
    }

    const float4 eav = ((const float4*)(ws + OFF_EAF))[e];
    const float sh0 = eav.x, s1x = eav.y, s1y = eav.z, s1z = eav.w;

    float o0[16], o1[24], t2a[8];
#pragma unroll
    for (int i = 0; i < 16; ++i) o0[i] = 0.f;
#pragma unroll
    for (int i = 0; i < 24; ++i) o1[i] = 0.f;
#pragma unroll
    for (int i = 0; i < 8; ++i) t2a[i] = 0.f;

#pragma unroll
    for (int c = 0; c < 16; c += 2) {
        accum48(A, h[c], sh0, s1x, s1y, s1z, o0, o1, t2a);
        if (c + 2 < 16) load48(A, Gp + (c + 2) * 12);
        accum48(B, h[c + 1], sh0, s1x, s1y, s1z, o0, o1, t2a);
        if (c + 3 < 16) load48(B, Gp + (c + 3) * 12);
    }

#pragma unroll
    for (int w = 0; w < 8; ++w) {
        o1[w * 3 + 0] = fmaf(t2a[w], s1x, o1[w * 3 + 0]);
        o1[w * 3 + 1] = fmaf(t2a[w], s1y, o1[w * 3 + 1]);
        o1[w * 3 + 2] = fmaf(t2a[w], s1z, o1[w * 3 + 2]);
    }

    if (pass == 0) {
        const float* pd = ws + OFF_P + dst * 40;
        float sc = 0.f;
#pragma unroll
        for (int j = 0; j < 16; ++j) sc = fmaf(o0[j], pd[j], sc);
#pragma unroll
        for (int j = 0; j < 24; ++j) sc = fmaf(o1[j], pd[16 + j], sc);
        sc = fminf(fmaxf(sc * KSCALE, -60.f), 60.f);
        float ct = 10.f * (1.f - d * 0.125f);
        float cutoff = (ct > 0.f) ? expf(-1.f / ct) : 0.f;
        float ev = fmaxf(cutoff * expf(sc), 0.f);
        ws[OFF_EXPV + dpos] = ev;                      /* dst-sorted slot */
        atomicAdd(ws + OFF_Z + dst, ev);
    } else {
        float* vr = ws + OFF_VBUF + (size_t)dpos * 40; /* dst-sorted slot */
#pragma unroll
        for (int j = 0; j < 16; ++j) vr[j] = sanitize(o0[j] * KSCALE);
#pragma unroll
        for (int j = 0; j < 24; ++j) vr[16 + j] = sanitize(o1[j] * KSCALE);
    }
}

// ---------------- gather: one thread per (node, feature-quad); float4 streaming ----------------
__global__ __launch_bounds__(256) void gather_kernel(
    const float* __restrict__ ws, void* __restrict__ out)
{
    const int i = blockIdx.x * 256 + threadIdx.x;
    if (i >= N_CNT * 10) return;
    const int n = i / 10;
    const int q = i - n * 10;
    const int* start = (const int*)(ws + OFF_START);
    const float* expv = ws + OFF_EXPV;
    const float4* Vbuf4 = (const float4*)(ws + OFF_VBUF);
    const int s = start[n], t = start[n + 1];

    float zz = ws[OFF_Z + n];
    const float rz = (zz > 0.f) ? 1.f / zz : 1.f;

    float ax = 0.f, ay = 0.f, az = 0.f, aw = 0.f;
    for (int j = s; j < t; ++j) {
        const float we = sqrtf(fmaxf(expv[j] * rz, 0.f));
        float4 v = Vbuf4[(size_t)j * 10 + q];
        ax = fmaf(we, v.x, ax); ay = fmaf(we, v.y, ay);
        az = fmaf(we, v.z, az); aw = fmaf(we, v.w, aw);
    }
    ax = sanitize(ax); ay = sanitize(ay); az = sanitize(az); aw = sanitize(aw);
    const int f32 = *(const int*)ws;
    if (f32) {
        float4 o; o.x = ax; o.y = ay; o.z = az; o.w = aw;
        ((float4*)out)[(size_t)n * 10 + q] = o;
    } else {
        uint2 o;
        o.x = (unsigned)f2bf(ax) | ((unsigned)f2bf(ay) << 16);
        o.y = (unsigned)f2bf(az) | ((unsigned)f2bf(aw) << 16);
        ((uint2*)out)[(size_t)n * 10 + q] = o;
    }
}

extern "C" void kernel_launch(void* const* d_in, const int* in_sizes, int n_in,
                              void* d_out, int out_size, void* d_ws, size_t ws_size,
                              hipStream_t stream)
{
    (void)in_sizes; (void)n_in; (void)out_size; (void)ws_size;
    const void* x   = d_in[0];
    const int*  ei  = (const int*)d_in[1];
    const void* ea  = d_in[2];
    const void* amf = d_in[5];
    const void* Wq0 = d_in[6];
    const void* Wq1 = d_in[7];
    const void* Wk1 = d_in[8];
    const void* Wk2 = d_in[9];
    const void* Wv1 = d_in[10];
    const void* Wv2 = d_in[11];
    const void* Wd0 = d_in[12];
    const void* Wd1 = d_in[13];

    float* ws = (float*)d_ws;

    hipMemsetAsync(ws + OFF_DEG, 0, 20000 * sizeof(int), stream);   /* DEG + DEG2 adjacent */
    prepgp_kernel<<<1915, 256, 0, stream>>>(x, ea, amf, Wq0, Wq1, Wk1, Wk2, Wv1, Wv2, Wd0, Wd1, ei, ws);
    scan_kernel<<<1, 512, 0, stream>>>(ws);
    fill_kernel<<<625, 256, 0, stream>>>(ei, ws);
    edge_kernel<<<2500, 128, 0, stream>>>(ei, ws);
    gather_kernel<<<(N_CNT * 10 + 255) / 256, 256, 0, stream>>>(ws, d_out);
}

// Round 14
// 283.944 us; speedup vs baseline: 1.0614x; 1.0614x over previous
//
#include <hip/hip_runtime.h>
#include <hip/hip_bf16.h>

#define E_CNT 160000
#define N_CNT 10000

#define INV_STEP   2.125f          /* 17/8 */
#define EMB_C      33.734292f      /* 1.14136 * e^2 * sqrt(16) */
#define INVS320    0.05590170f     /* 1/sqrt(320) */
#define INVS8      0.35355339f     /* 1/sqrt(8)   */
#define INV_SQRT3  0.57735027f
#define KSCALE     0.051031036f    /* 0.25 (w/sqrt16) * 1/sqrt(24) (fctp norm) */

/* ---- workspace layout (float-sized offsets) ---- */
#define OFF_FLAG   0          /* 16 floats reserved (int flag at [0]) */
#define OFF_EAF    400016     /* 640000 */
#define OFF_AMFF   1040016    /* 160000 */
#define OFF_WK1F   1200656    /* 256 */
#define OFF_WV1F   1200912    /* 256 */
#define OFF_P      1219600    /* 400000 */
#define OFF_EXPV   1619600    /* 160000 (dst-sorted order) */
#define OFF_VBUF   1779600    /* 6400000 (dst-sorted order) */
#define OFF_DEG    8179600    /* 10000 ints (dst); reused as Z (zeroed at end of scan) */
#define OFF_Z      8179600    /* alias of OFF_DEG */
#define OFF_DEG2   8189600    /* 10000 ints (src) -- adjacent to DEG: single memset */
#define OFF_START  8199600    /* 10001 ints */
#define OFF_START2 8209601    /* 10001 ints */
#define OFF_CURS   8219602    /* 10000 ints */
#define OFF_CURS2  8229602    /* 10000 ints */
#define OFF_DPOS   8239602    /* 160000 ints: dst-position of edge at src-sorted slot */
#define OFF_ELIST2 8399602    /* 160000 ints */
#define OFF_G      8559632    /* G planes: 32*12*10000 uint4 = 61.44 MB = 15,360,000 float slots */
/* total 23,919,632 floats = 95.7 MB (same extent as R5-R13 -- verified mapped) */

/* G plane layout (R14): element (n, p, c, q) at uint4 index
   ((p*16+c)*12+q)*10000 + n  ==  p*1920000 + c*120000 + q*10000 + n
   -> writer (consecutive n per wave) stores 1-KB coalesced;
   -> reader (lanes share/neighbor src) loads few adjacent lines per instr. */

static __device__ __forceinline__ float bf2f(__hip_bfloat16 b) { return __bfloat162float(b); }
static __device__ __forceinline__ float cvt(float v) { return v; }
static __device__ __forceinline__ float cvt(__hip_bfloat16 v) { return bf2f(v); }
static __device__ __forceinline__ float sanitize(float v) {
    return fminf(fmaxf(v, -1e30f), 1e30f);
}
static __device__ __forceinline__ unsigned short f2bf(float f) {
    unsigned x = __float_as_uint(f);
    unsigned r = (x + 0x7fffu + ((x >> 16) & 1u)) >> 16;   /* RN-even */
    return (unsigned short)r;
}
static __device__ __forceinline__ float bflo(unsigned u) { return __uint_as_float(u << 16); }
static __device__ __forceinline__ float bfhi(unsigned u) { return __uint_as_float(u & 0xffff0000u); }

/* load 4 consecutive floats from a maybe-bf16 / maybe-f32 buffer at element quad index i4 */
static __device__ __forceinline__ float4 load4(const void* p, int i4, int f32)
{
    if (f32) return ((const float4*)p)[i4];
    uint2 u = ((const uint2*)p)[i4];
    float4 r;
    r.x = bflo(u.x); r.y = bfhi(u.x);
    r.z = bflo(u.y); r.w = bfhi(u.y);
    return r;
}

/* 8-wide vector load: bf16 = one uint4 (16 B), f32 = two float4. p must be 16B-aligned. */
static __device__ __forceinline__ void ld8(const float* p, float (&r)[8])
{
    float4 a = ((const float4*)p)[0];
    float4 b = ((const float4*)p)[1];
    r[0] = a.x; r[1] = a.y; r[2] = a.z; r[3] = a.w;
    r[4] = b.x; r[5] = b.y; r[6] = b.z; r[7] = b.w;
}
static __device__ __forceinline__ void ld8(const __hip_bfloat16* p, float (&r)[8])
{
    uint4 u = *(const uint4*)p;
    r[0] = bflo(u.x); r[1] = bfhi(u.x); r[2] = bflo(u.y); r[3] = bfhi(u.y);
    r[4] = bflo(u.z); r[5] = bfhi(u.z); r[6] = bflo(u.w); r[7] = bfhi(u.w);
}

// ---------------- detect: ONCE, 64 threads, shfl-reduce ----------------
__global__ void detect_kernel(const unsigned short* __restrict__ xb, int* __restrict__ flag)
{
    const int lane = threadIdx.x;                     /* 64 threads */
    unsigned e0 = (unsigned)((xb[2 * lane] >> 7) & 0xFF);        /* even u16 = fp32 low halves */
    unsigned e1 = (unsigned)((xb[128 + 2 * lane] >> 7) & 0xFF);
    int c = (e0 >= 141 ? 1 : 0) + (e1 >= 141 ? 1 : 0);
#pragma unroll
    for (int off = 1; off < 64; off <<= 1) c += __shfl_xor(c, off);
    if (lane == 0) *flag = (c >= 8) ? 1 : 0;          /* 1 = inputs are fp32 */
}

// ---------------- prep: ingest EA/AMF/W1 + degree atomics ----------------
__global__ __launch_bounds__(256) void prep_kernel(
    const void* __restrict__ ea, const void* __restrict__ amf,
    const void* __restrict__ Wk1, const void* __restrict__ Wv1,
    const int* __restrict__ ei, float* __restrict__ ws)
{
    const int f32 = *(const int*)ws;
    const int i = blockIdx.x * 256 + threadIdx.x;     /* 625 blocks -> 160000 threads */
    if (i < 160000) ((float4*)(ws + OFF_EAF))[i] = load4(ea, i, f32);
    if (i < 40000) {
        ((float4*)(ws + OFF_AMFF))[i] = load4(amf, i, f32);
#pragma unroll
        for (int k = 0; k < 4; ++k) {
            atomicAdd((int*)(ws + OFF_DEG)  + ei[E_CNT + 4 * i + k], 1);   /* dst degree */
            atomicAdd((int*)(ws + OFF_DEG2) + ei[4 * i + k], 1);           /* src degree */
        }
    }
    if (i < 64) {
        ((float4*)(ws + OFF_WK1F))[i] = load4(Wk1, i, f32);
        ((float4*)(ws + OFF_WV1F))[i] = load4(Wv1, i, f32);
    }
}

// ---------------- G builder: vectorized loads, PLANE-TRANSPOSED coalesced stores ----------------
template <typename T>
static __device__ __forceinline__ void build_G(
    const T* __restrict__ x, const T* __restrict__ W2b, int n, int p, int c, float* __restrict__ ws)
{
    float xs[40];
#pragma unroll
    for (int q = 0; q < 5; ++q) ld8(x + n * 40 + q * 8, *(float(*)[8])(xs + q * 8));
    const T* W2 = W2b + c * 576;

    float out[96];
#pragma unroll
    for (int k = 0; k < 96; ++k) out[k] = 0.f;

    /* seg1: W2[u*16+w], w=0..15 -> out[0..15] */
#pragma unroll
    for (int u = 0; u < 16; ++u) {
        float r0[8], r1[8];
        ld8(W2 + u * 16, r0);
        ld8(W2 + u * 16 + 8, r1);
        const float xv = xs[u];
#pragma unroll
        for (int w = 0; w < 8; ++w) {
            out[w]     = fmaf(r0[w], xv, out[w]);
            out[8 + w] = fmaf(r1[w], xv, out[8 + w]);
        }
    }
    /* seg2: W2[256+u*8+w] -> out[16..23] */
#pragma unroll
    for (int u = 0; u < 16; ++u) {
        float r[8];
        ld8(W2 + 256 + u * 8, r);
        const float xv = xs[u];
#pragma unroll
        for (int w = 0; w < 8; ++w) out[16 + w] = fmaf(r[w], xv, out[16 + w]);
    }
    /* seg3: W2[384+u*8+w] x1[u] -> out[24+w*3+i] */
#pragma unroll
    for (int u = 0; u < 8; ++u) {
        float r[8];
        ld8(W2 + 384 + u * 8, r);
        const float a0 = xs[16 + u * 3 + 0];
        const float a1 = xs[16 + u * 3 + 1];
        const float a2 = xs[16 + u * 3 + 2];
#pragma unroll
        for (int w = 0; w < 8; ++w) {
            out[24 + w * 3 + 0] = fmaf(r[w], a0, out[24 + w * 3 + 0]);
            out[24 + w * 3 + 1] = fmaf(r[w], a1, out[24 + w * 3 + 1]);
            out[24 + w * 3 + 2] = fmaf(r[w], a2, out[24 + w * 3 + 2]);
        }
    }
    /* seg4: W2[448+u*16+w] x1[u] -> out[48+w*3+i] (scaled by 1/sqrt3 below) */
#pragma unroll
    for (int u = 0; u < 8; ++u) {
        float r0[8], r1[8];
        ld8(W2 + 448 + u * 16, r0);
        ld8(W2 + 448 + u * 16 + 8, r1);
        const float a0 = xs[16 + u * 3 + 0];
        const float a1 = xs[16 + u * 3 + 1];
        const float a2 = xs[16 + u * 3 + 2];
#pragma unroll
        for (int w = 0; w < 8; ++w) {
            out[48 + w * 3 + 0] = fmaf(r0[w], a0, out[48 + w * 3 + 0]);
            out[48 + w * 3 + 1] = fmaf(r0[w], a1, out[48 + w * 3 + 1]);
            out[48 + w * 3 + 2] = fmaf(r0[w], a2, out[48 + w * 3 + 2]);
            out[48 + (8 + w) * 3 + 0] = fmaf(r1[w], a0, out[48 + (8 + w) * 3 + 0]);
            out[48 + (8 + w) * 3 + 1] = fmaf(r1[w], a1, out[48 + (8 + w) * 3 + 1]);
            out[48 + (8 + w) * 3 + 2] = fmaf(r1[w], a2, out[48 + (8 + w) * 3 + 2]);
        }
    }
#pragma unroll
    for (int k = 0; k < 48; ++k) out[48 + k] *= INV_SQRT3;

    uint4 ov[12];
    unsigned* ou = (unsigned*)ov;
#pragma unroll
    for (int k = 0; k < 48; ++k)
        ou[k] = (unsigned)f2bf(out[2 * k]) | ((unsigned)f2bf(out[2 * k + 1]) << 16);
    /* plane-transposed store: lanes (consecutive n) -> contiguous 1-KB per instr */
    uint4* gb = (uint4*)(ws + OFF_G) + (size_t)(p * 16 + c) * 120000 + n;
#pragma unroll
    for (int q = 0; q < 12; ++q) gb[q * 10000] = ov[q];
}

// ---------------- P builder (vectorized loads) ----------------
template <typename T>
static __device__ __forceinline__ void build_P(
    const T* __restrict__ x, const T* __restrict__ Wq0, const T* __restrict__ Wq1,
    const T* __restrict__ Wd0, const T* __restrict__ Wd1, int n, float* __restrict__ ws)
{
    float xs[40];
#pragma unroll
    for (int q = 0; q < 5; ++q) ld8(x + n * 40 + q * 8, *(float(*)[8])(xs + q * 8));

    float q0[16];
#pragma unroll
    for (int w = 0; w < 16; ++w) q0[w] = 0.f;
#pragma unroll
    for (int u = 0; u < 16; ++u) {
        float r0[8], r1[8];
        ld8(Wq0 + u * 16, r0);
        ld8(Wq0 + u * 16 + 8, r1);
        const float xv = xs[u];
#pragma unroll
        for (int w = 0; w < 8; ++w) {
            q0[w]     = fmaf(r0[w], xv, q0[w]);
            q0[8 + w] = fmaf(r1[w], xv, q0[8 + w]);
        }
    }
#pragma unroll
    for (int w = 0; w < 16; ++w) q0[w] *= 0.25f;

    float p0[16];
#pragma unroll
    for (int v = 0; v < 16; ++v) p0[v] = 0.f;
#pragma unroll
    for (int w = 0; w < 16; ++w) {
        float r0[8], r1[8];
        ld8(Wd0 + w * 16, r0);
        ld8(Wd0 + w * 16 + 8, r1);
        const float qv = q0[w];
#pragma unroll
        for (int v = 0; v < 8; ++v) {
            p0[v]     = fmaf(r0[v], qv, p0[v]);
            p0[8 + v] = fmaf(r1[v], qv, p0[8 + v]);
        }
    }
    float* pn = ws + OFF_P + n * 40;
#pragma unroll
    for (int v = 0; v < 16; ++v) pn[v] = sanitize(p0[v] * INVS320);

    float q1[24];
#pragma unroll
    for (int k = 0; k < 24; ++k) q1[k] = 0.f;
#pragma unroll
    for (int u = 0; u < 8; ++u) {
        float r[8];
        ld8(Wq1 + u * 8, r);
        const float a0 = xs[16 + u * 3 + 0];
        const float a1 = xs[16 + u * 3 + 1];
        const float a2 = xs[16 + u * 3 + 2];
#pragma unroll
        for (int w = 0; w < 8; ++w) {
            q1[w * 3 + 0] = fmaf(r[w], a0, q1[w * 3 + 0]);
            q1[w * 3 + 1] = fmaf(r[w], a1, q1[w * 3 + 1]);
            q1[w * 3 + 2] = fmaf(r[w], a2, q1[w * 3 + 2]);
        }
    }
#pragma unroll
    for (int k = 0; k < 24; ++k) q1[k] *= INVS8;

    float p1[24];
#pragma unroll
    for (int k = 0; k < 24; ++k) p1[k] = 0.f;
#pragma unroll
    for (int w = 0; w < 8; ++w) {
        float r[8];
        ld8(Wd1 + w * 8, r);
        const float b0 = q1[w * 3 + 0];
        const float b1 = q1[w * 3 + 1];
        const float b2 = q1[w * 3 + 2];
#pragma unroll
        for (int v = 0; v < 8; ++v) {
            p1[v * 3 + 0] = fmaf(r[v], b0, p1[v * 3 + 0]);
            p1[v * 3 + 1] = fmaf(r[v], b1, p1[v * 3 + 1]);
            p1[v * 3 + 2] = fmaf(r[v], b2, p1[v * 3 + 2]);
        }
    }
    const float sc = INVS320 * INV_SQRT3;
#pragma unroll
    for (int k = 0; k < 24; ++k) pn[16 + k] = sanitize(p1[k] * sc);
}

// ---------------- gp: [0,1250) G | [1250,1290) P ----------------
__global__ __launch_bounds__(256) void gp_kernel(
    const void* __restrict__ x,
    const void* __restrict__ Wq0, const void* __restrict__ Wq1,
    const void* __restrict__ Wk2, const void* __restrict__ Wv2,
    const void* __restrict__ Wd0, const void* __restrict__ Wd1,
    float* __restrict__ ws)
{
    const int f32 = *(const int*)ws;
    const int tid = threadIdx.x;
    const int blk = blockIdx.x;
    if (blk < 1250) {
        const int t = blk * 256 + tid;               /* < 320000 */
        const int p   = t / 160000;
        const int rem = t - p * 160000;
        const int c   = rem / 10000;
        const int n   = rem - c * 10000;
        const void* W2b = p ? Wv2 : Wk2;
        if (f32) build_G((const float*)x, (const float*)W2b, n, p, c, ws);
        else     build_G((const __hip_bfloat16*)x, (const __hip_bfloat16*)W2b, n, p, c, ws);
        return;
    }
    {
        const int n = (blk - 1250) * 256 + tid;
        if (n >= N_CNT) return;
        if (f32) build_P((const float*)x, (const float*)Wq0, (const float*)Wq1,
                         (const float*)Wd0, (const float*)Wd1, n, ws);
        else     build_P((const __hip_bfloat16*)x, (const __hip_bfloat16*)Wq0,
                         (const __hip_bfloat16*)Wq1, (const __hip_bfloat16*)Wd0,
                         (const __hip_bfloat16*)Wd1, n, ws);
    }
}

// ---------------- dual scan (512 threads: half dst, half src) + zero Z at end ----------------
__global__ __launch_bounds__(512) void scan_kernel(float* __restrict__ ws)
{
    __shared__ int ssum[512];
    const int t    = threadIdx.x;
    const int half = t >> 8;
    const int lt   = t & 255;
    int* deg   = (int*)(ws + (half ? OFF_DEG2   : OFF_DEG));
    int* start = (int*)(ws + (half ? OFF_START2 : OFF_START));
    int* curs  = (int*)(ws + (half ? OFF_CURS2  : OFF_CURS));
    const int base = lt * 40;
    int s = 0;
    for (int k = 0; k < 40; ++k) {
        int idx = base + k;
        if (idx < N_CNT) s += deg[idx];
    }
    ssum[t] = s;
    __syncthreads();
    for (int off = 1; off < 256; off <<= 1) {
        int v = (lt >= off) ? ssum[t - off] : 0;
        __syncthreads();
        ssum[t] += v;
        __syncthreads();
    }
    int run = ssum[t] - s;
    for (int k = 0; k < 40; ++k) {
        int idx = base + k;
        if (idx < N_CNT) {
            start[idx] = run;
            curs[idx]  = run;
            run += deg[idx];
        }
    }
    if (lt == 255) start[N_CNT] = E_CNT;
    __syncthreads();                                   /* all deg reads done */
    for (int k = t; k < N_CNT; k += 512) ws[OFF_Z + k] = 0.f;   /* Z aliases DEG */
}

// ---------------- fill: src-CSR + dst-position per src-slot ----------------
__global__ __launch_bounds__(256) void fill_kernel(const int* __restrict__ ei, float* __restrict__ ws)
{
    const int e = blockIdx.x * 256 + threadIdx.x;      /* 625*256 = 160000 exact */
    int pd = atomicAdd((int*)(ws + OFF_CURS)  + ei[E_CNT + e], 1);
    int ps = atomicAdd((int*)(ws + OFF_CURS2) + ei[e], 1);
    ((int*)(ws + OFF_ELIST2))[ps] = e;
    ((int*)(ws + OFF_DPOS))[ps]   = pd;
}

// ---------------- edge-kernel helpers ----------------
/* plane-strided load: 12 uint4 at stride 10000 uint4 (160 KB) */
static __device__ __forceinline__ void load48p(unsigned (&ub)[48], const uint4* __restrict__ p0)
{
#pragma unroll
    for (int q = 0; q < 12; ++q) {
        uint4 v = p0[(size_t)q * 10000];
        ub[4 * q + 0] = v.x; ub[4 * q + 1] = v.y;
        ub[4 * q + 2] = v.z; ub[4 * q + 3] = v.w;
    }
}

/* consumption strictly in load (FIFO) order: k = 0..95 monotone */
static __device__ __forceinline__ void accum48(const unsigned (&ub)[48], float hc, float sh0,
    float s1x, float s1y, float s1z,
    float (&o0)[16], float (&o1)[24], float (&t2a)[8])
{
    const float hs = hc * sh0;
#define GVAL(k) (((k) & 1) ? bfhi(ub[(k) >> 1]) : bflo(ub[(k) >> 1]))
#pragma unroll
    for (int w = 0; w < 16; ++w) o0[w] = fmaf(hs, GVAL(w), o0[w]);
#pragma unroll
    for (int w = 0; w < 8; ++w) t2a[w] = fmaf(hc, GVAL(16 + w), t2a[w]);
#pragma unroll
    for (int k = 0; k < 24; ++k) o1[k] = fmaf(hs, GVAL(24 + k), o1[k]);
#pragma unroll
    for (int w = 0; w < 16; ++w) {
        float g = GVAL(48 + w * 3 + 0) * s1x;
        g = fmaf(GVAL(48 + w * 3 + 1), s1y, g);
        g = fmaf(GVAL(48 + w * 3 + 2), s1z, g);
        o0[w] = fmaf(hc, g, o0[w]);
    }
#undef GVAL
}

// ---------------- per-edge main kernel: R12 winner + plane-layout reads ----------------
__global__ __launch_bounds__(128, 2) void edge_kernel(
    const int* __restrict__ ei, float* __restrict__ ws)
{
    const int tid  = threadIdx.x;
    const int pass = tid >> 6;          /* wave 0: K, wave 1: V */
    const int lane = tid & 63;
    /* XCD swizzle: give each XCD a contiguous src range (2496 = 8*312) */
    const int b  = blockIdx.x;
    const int lb = (b < 2496) ? ((b & 7) * 312 + (b >> 3)) : b;
    const int sidx = lb * 64 + lane;    /* src-sorted edge index; 2500*64 = 160000 exact */
    const int e    = ((const int*)(ws + OFF_ELIST2))[sidx];
    const int dpos = ((const int*)(ws + OFF_DPOS))[sidx];
    const int src  = ei[e];
    const int dst  = ei[E_CNT + e];

    /* plane-layout base for this (src, pass): c-chunk at +c*120000, q at +q*10000 */
    const uint4* gb = (const uint4*)(ws + OFF_G) + (size_t)pass * 1920000 + src;
    /* issue the first two G row-chunks NOW -- everything below overlaps their latency */
    unsigned A[48], B[48];
    load48p(A, gb);
    load48p(B, gb + 120000);

    const float d   = ws[OFF_AMFF + e];
    const float dsv = d * INV_STEP;
    float emb[16];
#pragma unroll
    for (int bb = 0; bb < 16; ++bb) {
        float t1 = dsv - (float)bb;
        float t2 = (float)(bb + 2) - dsv;
        float v = 0.f;
        if (t1 > 0.f && t2 > 0.f) v = EMB_C * expf(-1.f / t1 - 1.f / t2);
        emb[bb] = v;
    }

    const float* W1 = ws + (pass ? OFF_WV1F : OFF_WK1F);
    float h[16];
#pragma unroll
    for (int j = 0; j < 16; ++j) {
        float s = 0.f;
#pragma unroll
        for (int bb = 0; bb < 16; ++bb) s = fmaf(emb[bb], W1[bb * 16 + j], s);
        s *= 0.25f;
        h[j] = s / (1.f + expf(-s));
    }

    const float4 eav = ((const float4*)(ws + OFF_EAF))[e];
    const float sh0 = eav.x, s1x = eav.y, s1y = eav.z, s1z = eav.w;

    float o0[16], o1[24], t2a[8];
#pragma unroll
    for (int i = 0; i < 16; ++i) o0[i] = 0.f;
#pragma unroll
    for (int i = 0; i < 24; ++i) o1[i] = 0.f;
#pragma unroll
    for (int i = 0; i < 8; ++i) t2a[i] = 0.f;

#pragma unroll
    for (int c = 0; c < 16; c += 2) {
        accum48(A, h[c], sh0, s1x, s1y, s1z, o0, o1, t2a);
        if (c + 2 < 16) load48p(A, gb + (size_t)(c + 2) * 120000);
        accum48(B, h[c + 1], sh0, s1x, s1y, s1z, o0, o1, t2a);
        if (c + 3 < 16) load48p(B, gb + (size_t)(c + 3) * 120000);
    }

#pragma unroll
    for (int w = 0; w < 8; ++w) {
        o1[w * 3 + 0] = fmaf(t2a[w], s1x, o1[w * 3 + 0]);
        o1[w * 3 + 1] = fmaf(t2a[w], s1y, o1[w * 3 + 1]);
        o1[w * 3 + 2] = fmaf(t2a[w], s1z, o1[w * 3 + 2]);
    }

    if (pass == 0) {
        const float* pd = ws + OFF_P + dst * 40;
        float sc = 0.f;
#pragma unroll
        for (int j = 0; j < 16; ++j) sc = fmaf(o0[j], pd[j], sc);
#pragma unroll
        for (int j = 0; j < 24; ++j) sc = fmaf(o1[j], pd[16 + j], sc);
        sc = fminf(fmaxf(sc * KSCALE, -60.f), 60.f);
        float ct = 10.f * (1.f - d * 0.125f);
        float cutoff = (ct > 0.f) ? expf(-1.f / ct) : 0.f;
        float ev = fmaxf(cutoff * expf(sc), 0.f);
        ws[OFF_EXPV + dpos] = ev;                      /* dst-sorted slot */
        atomicAdd(ws + OFF_Z + dst, ev);
    } else {
        float* vr = ws + OFF_VBUF + (size_t)dpos * 40; /* dst-sorted slot */
#pragma unroll
        for (int j = 0; j < 16; ++j) vr[j] = sanitize(o0[j] * KSCALE);
#pragma unroll
        for (int j = 0; j < 24; ++j) vr[16 + j] = sanitize(o1[j] * KSCALE);
    }
}

// ---------------- gather: one thread per (node, feature-quad); float4 streaming ----------------
__global__ __launch_bounds__(256) void gather_kernel(
    const float* __restrict__ ws, void* __restrict__ out)
{
    const int i = blockIdx.x * 256 + threadIdx.x;
    if (i >= N_CNT * 10) return;
    const int n = i / 10;
    const int q = i - n * 10;
    const int* start = (const int*)(ws + OFF_START);
    const float* expv = ws + OFF_EXPV;
    const float4* Vbuf4 = (const float4*)(ws + OFF_VBUF);
    const int s = start[n], t = start[n + 1];

    float zz = ws[OFF_Z + n];
    const float rz = (zz > 0.f) ? 1.f / zz : 1.f;

    float ax = 0.f, ay = 0.f, az = 0.f, aw = 0.f;
    for (int j = s; j < t; ++j) {
        const float we = sqrtf(fmaxf(expv[j] * rz, 0.f));
        float4 v = Vbuf4[(size_t)j * 10 + q];
        ax = fmaf(we, v.x, ax); ay = fmaf(we, v.y, ay);
        az = fmaf(we, v.z, az); aw = fmaf(we, v.w, aw);
    }
    ax = sanitize(ax); ay = sanitize(ay); az = sanitize(az); aw = sanitize(aw);
    const int f32 = *(const int*)ws;
    if (f32) {
        float4 o; o.x = ax; o.y = ay; o.z = az; o.w = aw;
        ((float4*)out)[(size_t)n * 10 + q] = o;
    } else {
        uint2 o;
        o.x = (unsigned)f2bf(ax) | ((unsigned)f2bf(ay) << 16);
        o.y = (unsigned)f2bf(az) | ((unsigned)f2bf(aw) << 16);
        ((uint2*)out)[(size_t)n * 10 + q] = o;
    }
}

extern "C" void kernel_launch(void* const* d_in, const int* in_sizes, int n_in,
                              void* d_out, int out_size, void* d_ws, size_t ws_size,
                              hipStream_t stream)
{
    (void)in_sizes; (void)n_in; (void)out_size; (void)ws_size;
    const void* x   = d_in[0];
    const int*  ei  = (const int*)d_in[1];
    const void* ea  = d_in[2];
    const void* amf = d_in[5];
    const void* Wq0 = d_in[6];
    const void* Wq1 = d_in[7];
    const void* Wk1 = d_in[8];
    const void* Wk2 = d_in[9];
    const void* Wv1 = d_in[10];
    const void* Wv2 = d_in[11];
    const void* Wd0 = d_in[12];
    const void* Wd1 = d_in[13];

    float* ws = (float*)d_ws;

    hipMemsetAsync(ws + OFF_DEG, 0, 20000 * sizeof(int), stream);   /* DEG + DEG2 adjacent */
    detect_kernel<<<1, 64, 0, stream>>>((const unsigned short*)x, (int*)ws);
    prep_kernel<<<625, 256, 0, stream>>>(ea, amf, Wk1, Wv1, ei, ws);
    gp_kernel<<<1290, 256, 0, stream>>>(x, Wq0, Wq1, Wk2, Wv2, Wd0, Wd1, ws);
    scan_kernel<<<1, 512, 0, stream>>>(ws);
    fill_kernel<<<625, 256, 0, stream>>>(ei, ws);
    edge_kernel<<<2500, 128, 0, stream>>>(ei, ws);
    gather_kernel<<<(N_CNT * 10 + 255) / 256, 256, 0, stream>>>(ws, d_out);
}

// Round 15
// 283.592 us; speedup vs baseline: 1.0627x; 1.0012x over previous
//
#include <hip/hip_runtime.h>
#include <hip/hip_bf16.h>

#define E_CNT 160000
#define N_CNT 10000

#define INV_STEP   2.125f          /* 17/8 */
#define EMB_C      33.734292f      /* 1.14136 * e^2 * sqrt(16) */
#define INVS320    0.05590170f     /* 1/sqrt(320) */
#define INVS8      0.35355339f     /* 1/sqrt(8)   */
#define INV_SQRT3  0.57735027f
#define KSCALE     0.051031036f    /* 0.25 (w/sqrt16) * 1/sqrt(24) (fctp norm) */

/* ---- workspace layout (float-sized offsets) ---- */
#define OFF_FLAG   0          /* 16 floats reserved (int flag at [0]) */
#define OFF_EAF    400016     /* 640000 */
#define OFF_AMFF   1040016    /* 160000 */
#define OFF_WK1F   1200656    /* 256 */
#define OFF_WV1F   1200912    /* 256 */
#define OFF_P      1219600    /* 400000 */
#define OFF_EXPV   1619600    /* 160000 (dst-sorted order, fp32) */
#define OFF_VBUF   1779600    /* E*40 bf16 = 12.8 MB (dst-sorted order) -- was fp32 */
#define OFF_DEG    8179600    /* 10000 ints (dst); reused as Z (zeroed at end of scan) */
#define OFF_Z      8179600    /* alias of OFF_DEG */
#define OFF_DEG2   8189600    /* 10000 ints (src) -- adjacent to DEG: single memset */
#define OFF_START  8199600    /* 10001 ints */
#define OFF_START2 8209601    /* 10001 ints */
#define OFF_CURS   8219602    /* 10000 ints */
#define OFF_CURS2  8229602    /* 10000 ints */
#define OFF_DPOS   8239602    /* 160000 ints: dst-position of edge at src-sorted slot */
#define OFF_ELIST2 8399602    /* 160000 ints */
#define OFF_G      8559632    /* G planes: 32*12*10000 uint4 = 61.44 MB */
/* total 23,919,632 floats = 95.7 MB (same extent as R5-R14 -- verified mapped) */

/* G plane layout: element (n, p, c, q) at uint4 index p*1920000 + c*120000 + q*10000 + n */

static __device__ __forceinline__ float bf2f(__hip_bfloat16 b) { return __bfloat162float(b); }
static __device__ __forceinline__ float cvt(float v) { return v; }
static __device__ __forceinline__ float cvt(__hip_bfloat16 v) { return bf2f(v); }
static __device__ __forceinline__ float sanitize(float v) {
    return fminf(fmaxf(v, -1e30f), 1e30f);
}
static __device__ __forceinline__ unsigned short f2bf(float f) {
    unsigned x = __float_as_uint(f);
    unsigned r = (x + 0x7fffu + ((x >> 16) & 1u)) >> 16;   /* RN-even */
    return (unsigned short)r;
}
static __device__ __forceinline__ float bflo(unsigned u) { return __uint_as_float(u << 16); }
static __device__ __forceinline__ float bfhi(unsigned u) { return __uint_as_float(u & 0xffff0000u); }
/* pair convert: hopes for v_cvt_pk_f32_bf16 on gfx950; worst case = 2 ops (same as manual) */
static __device__ __forceinline__ float2 bfp(unsigned u) {
    __hip_bfloat162 b = *(__hip_bfloat162*)&u;
    return __bfloat1622float2(b);
}

/* load 4 consecutive floats from a maybe-bf16 / maybe-f32 buffer at element quad index i4 */
static __device__ __forceinline__ float4 load4(const void* p, int i4, int f32)
{
    if (f32) return ((const float4*)p)[i4];
    uint2 u = ((const uint2*)p)[i4];
    float4 r;
    r.x = bflo(u.x); r.y = bfhi(u.x);
    r.z = bflo(u.y); r.w = bfhi(u.y);
    return r;
}

/* 8-wide vector load: bf16 = one uint4 (16 B), f32 = two float4. p must be 16B-aligned. */
static __device__ __forceinline__ void ld8(const float* p, float (&r)[8])
{
    float4 a = ((const float4*)p)[0];
    float4 b = ((const float4*)p)[1];
    r[0] = a.x; r[1] = a.y; r[2] = a.z; r[3] = a.w;
    r[4] = b.x; r[5] = b.y; r[6] = b.z; r[7] = b.w;
}
static __device__ __forceinline__ void ld8(const __hip_bfloat16* p, float (&r)[8])
{
    uint4 u = *(const uint4*)p;
    r[0] = bflo(u.x); r[1] = bfhi(u.x); r[2] = bflo(u.y); r[3] = bfhi(u.y);
    r[4] = bflo(u.z); r[5] = bfhi(u.z); r[6] = bflo(u.w); r[7] = bfhi(u.w);
}

// ---------------- detect: ONCE, 64 threads, shfl-reduce ----------------
__global__ void detect_kernel(const unsigned short* __restrict__ xb, int* __restrict__ flag)
{
    const int lane = threadIdx.x;                     /* 64 threads */
    unsigned e0 = (unsigned)((xb[2 * lane] >> 7) & 0xFF);        /* even u16 = fp32 low halves */
    unsigned e1 = (unsigned)((xb[128 + 2 * lane] >> 7) & 0xFF);
    int c = (e0 >= 141 ? 1 : 0) + (e1 >= 141 ? 1 : 0);
#pragma unroll
    for (int off = 1; off < 64; off <<= 1) c += __shfl_xor(c, off);
    if (lane == 0) *flag = (c >= 8) ? 1 : 0;          /* 1 = inputs are fp32 */
}

// ---------------- prep: ingest EA/AMF/W1 + degree atomics ----------------
__global__ __launch_bounds__(256) void prep_kernel(
    const void* __restrict__ ea, const void* __restrict__ amf,
    const void* __restrict__ Wk1, const void* __restrict__ Wv1,
    const int* __restrict__ ei, float* __restrict__ ws)
{
    const int f32 = *(const int*)ws;
    const int i = blockIdx.x * 256 + threadIdx.x;     /* 625 blocks -> 160000 threads */
    if (i < 160000) ((float4*)(ws + OFF_EAF))[i] = load4(ea, i, f32);
    if (i < 40000) {
        ((float4*)(ws + OFF_AMFF))[i] = load4(amf, i, f32);
#pragma unroll
        for (int k = 0; k < 4; ++k) {
            atomicAdd((int*)(ws + OFF_DEG)  + ei[E_CNT + 4 * i + k], 1);   /* dst degree */
            atomicAdd((int*)(ws + OFF_DEG2) + ei[4 * i + k], 1);           /* src degree */
        }
    }
    if (i < 64) {
        ((float4*)(ws + OFF_WK1F))[i] = load4(Wk1, i, f32);
        ((float4*)(ws + OFF_WV1F))[i] = load4(Wv1, i, f32);
    }
}

// ---------------- G builder: vectorized loads, plane-transposed coalesced stores ----------------
template <typename T>
static __device__ __forceinline__ void build_G(
    const T* __restrict__ x, const T* __restrict__ W2b, int n, int p, int c, float* __restrict__ ws)
{
    float xs[40];
#pragma unroll
    for (int q = 0; q < 5; ++q) ld8(x + n * 40 + q * 8, *(float(*)[8])(xs + q * 8));
    const T* W2 = W2b + c * 576;

    float out[96];
#pragma unroll
    for (int k = 0; k < 96; ++k) out[k] = 0.f;

    /* seg1 */
#pragma unroll
    for (int u = 0; u < 16; ++u) {
        float r0[8], r1[8];
        ld8(W2 + u * 16, r0);
        ld8(W2 + u * 16 + 8, r1);
        const float xv = xs[u];
#pragma unroll
        for (int w = 0; w < 8; ++w) {
            out[w]     = fmaf(r0[w], xv, out[w]);
            out[8 + w] = fmaf(r1[w], xv, out[8 + w]);
        }
    }
    /* seg2 */
#pragma unroll
    for (int u = 0; u < 16; ++u) {
        float r[8];
        ld8(W2 + 256 + u * 8, r);
        const float xv = xs[u];
#pragma unroll
        for (int w = 0; w < 8; ++w) out[16 + w] = fmaf(r[w], xv, out[16 + w]);
    }
    /* seg3 */
#pragma unroll
    for (int u = 0; u < 8; ++u) {
        float r[8];
        ld8(W2 + 384 + u * 8, r);
        const float a0 = xs[16 + u * 3 + 0];
        const float a1 = xs[16 + u * 3 + 1];
        const float a2 = xs[16 + u * 3 + 2];
#pragma unroll
        for (int w = 0; w < 8; ++w) {
            out[24 + w * 3 + 0] = fmaf(r[w], a0, out[24 + w * 3 + 0]);
            out[24 + w * 3 + 1] = fmaf(r[w], a1, out[24 + w * 3 + 1]);
            out[24 + w * 3 + 2] = fmaf(r[w], a2, out[24 + w * 3 + 2]);
        }
    }
    /* seg4 (scaled by 1/sqrt3 below) */
#pragma unroll
    for (int u = 0; u < 8; ++u) {
        float r0[8], r1[8];
        ld8(W2 + 448 + u * 16, r0);
        ld8(W2 + 448 + u * 16 + 8, r1);
        const float a0 = xs[16 + u * 3 + 0];
        const float a1 = xs[16 + u * 3 + 1];
        const float a2 = xs[16 + u * 3 + 2];
#pragma unroll
        for (int w = 0; w < 8; ++w) {
            out[48 + w * 3 + 0] = fmaf(r0[w], a0, out[48 + w * 3 + 0]);
            out[48 + w * 3 + 1] = fmaf(r0[w], a1, out[48 + w * 3 + 1]);
            out[48 + w * 3 + 2] = fmaf(r0[w], a2, out[48 + w * 3 + 2]);
            out[48 + (8 + w) * 3 + 0] = fmaf(r1[w], a0, out[48 + (8 + w) * 3 + 0]);
            out[48 + (8 + w) * 3 + 1] = fmaf(r1[w], a1, out[48 + (8 + w) * 3 + 1]);
            out[48 + (8 + w) * 3 + 2] = fmaf(r1[w], a2, out[48 + (8 + w) * 3 + 2]);
        }
    }
#pragma unroll
    for (int k = 0; k < 48; ++k) out[48 + k] *= INV_SQRT3;

    uint4 ov[12];
    unsigned* ou = (unsigned*)ov;
#pragma unroll
    for (int k = 0; k < 48; ++k)
        ou[k] = (unsigned)f2bf(out[2 * k]) | ((unsigned)f2bf(out[2 * k + 1]) << 16);
    uint4* gb = (uint4*)(ws + OFF_G) + (size_t)(p * 16 + c) * 120000 + n;
#pragma unroll
    for (int q = 0; q < 12; ++q) gb[q * 10000] = ov[q];
}

// ---------------- P builder (vectorized loads) ----------------
template <typename T>
static __device__ __forceinline__ void build_P(
    const T* __restrict__ x, const T* __restrict__ Wq0, const T* __restrict__ Wq1,
    const T* __restrict__ Wd0, const T* __restrict__ Wd1, int n, float* __restrict__ ws)
{
    float xs[40];
#pragma unroll
    for (int q = 0; q < 5; ++q) ld8(x + n * 40 + q * 8, *(float(*)[8])(xs + q * 8));

    float q0[16];
#pragma unroll
    for (int w = 0; w < 16; ++w) q0[w] = 0.f;
#pragma unroll
    for (int u = 0; u < 16; ++u) {
        float r0[8], r1[8];
        ld8(Wq0 + u * 16, r0);
        ld8(Wq0 + u * 16 + 8, r1);
        const float xv = xs[u];
#pragma unroll
        for (int w = 0; w < 8; ++w) {
            q0[w]     = fmaf(r0[w], xv, q0[w]);
            q0[8 + w] = fmaf(r1[w], xv, q0[8 + w]);
        }
    }
#pragma unroll
    for (int w = 0; w < 16; ++w) q0[w] *= 0.25f;

    float p0[16];
#pragma unroll
    for (int v = 0; v < 16; ++v) p0[v] = 0.f;
#pragma unroll
    for (int w = 0; w < 16; ++w) {
        float r0[8], r1[8];
        ld8(Wd0 + w * 16, r0);
        ld8(Wd0 + w * 16 + 8, r1);
        const float qv = q0[w];
#pragma unroll
        for (int v = 0; v < 8; ++v) {
            p0[v]     = fmaf(r0[v], qv, p0[v]);
            p0[8 + v] = fmaf(r1[v], qv, p0[8 + v]);
        }
    }
    float* pn = ws + OFF_P + n * 40;
#pragma unroll
    for (int v = 0; v < 16; ++v) pn[v] = sanitize(p0[v] * INVS320);

    float q1[24];
#pragma unroll
    for (int k = 0; k < 24; ++k) q1[k] = 0.f;
#pragma unroll
    for (int u = 0; u < 8; ++u) {
        float r[8];
        ld8(Wq1 + u * 8, r);
        const float a0 = xs[16 + u * 3 + 0];
        const float a1 = xs[16 + u * 3 + 1];
        const float a2 = xs[16 + u * 3 + 2];
#pragma unroll
        for (int w = 0; w < 8; ++w) {
            q1[w * 3 + 0] = fmaf(r[w], a0, q1[w * 3 + 0]);
            q1[w * 3 + 1] = fmaf(r[w], a1, q1[w * 3 + 1]);
            q1[w * 3 + 2] = fmaf(r[w], a2, q1[w * 3 + 2]);
        }
    }
#pragma unroll
    for (int k = 0; k < 24; ++k) q1[k] *= INVS8;

    float p1[24];
#pragma unroll
    for (int k = 0; k < 24; ++k) p1[k] = 0.f;
#pragma unroll
    for (int w = 0; w < 8; ++w) {
        float r[8];
        ld8(Wd1 + w * 8, r);
        const float b0 = q1[w * 3 + 0];
        const float b1 = q1[w * 3 + 1];
        const float b2 = q1[w * 3 + 2];
#pragma unroll
        for (int v = 0; v < 8; ++v) {
            p1[v * 3 + 0] = fmaf(r[v], b0, p1[v * 3 + 0]);
            p1[v * 3 + 1] = fmaf(r[v], b1, p1[v * 3 + 1]);
            p1[v * 3 + 2] = fmaf(r[v], b2, p1[v * 3 + 2]);
        }
    }
    const float sc = INVS320 * INV_SQRT3;
#pragma unroll
    for (int k = 0; k < 24; ++k) pn[16 + k] = sanitize(p1[k] * sc);
}

// ---------------- gp: [0,1250) G | [1250,1290) P ----------------
__global__ __launch_bounds__(256) void gp_kernel(
    const void* __restrict__ x,
    const void* __restrict__ Wq0, const void* __restrict__ Wq1,
    const void* __restrict__ Wk2, const void* __restrict__ Wv2,
    const void* __restrict__ Wd0, const void* __restrict__ Wd1,
    float* __restrict__ ws)
{
    const int f32 = *(const int*)ws;
    const int tid = threadIdx.x;
    const int blk = blockIdx.x;
    if (blk < 1250) {
        const int t = blk * 256 + tid;               /* < 320000 */
        const int p   = t / 160000;
        const int rem = t - p * 160000;
        const int c   = rem / 10000;
        const int n   = rem - c * 10000;
        const void* W2b = p ? Wv2 : Wk2;
        if (f32) build_G((const float*)x, (const float*)W2b, n, p, c, ws);
        else     build_G((const __hip_bfloat16*)x, (const __hip_bfloat16*)W2b, n, p, c, ws);
        return;
    }
    {
        const int n = (blk - 1250) * 256 + tid;
        if (n >= N_CNT) return;
        if (f32) build_P((const float*)x, (const float*)Wq0, (const float*)Wq1,
                         (const float*)Wd0, (const float*)Wd1, n, ws);
        else     build_P((const __hip_bfloat16*)x, (const __hip_bfloat16*)Wq0,
                         (const __hip_bfloat16*)Wq1, (const __hip_bfloat16*)Wd0,
                         (const __hip_bfloat16*)Wd1, n, ws);
    }
}

// ---------------- dual scan (512 threads: half dst, half src) + zero Z at end ----------------
__global__ __launch_bounds__(512) void scan_kernel(float* __restrict__ ws)
{
    __shared__ int ssum[512];
    const int t    = threadIdx.x;
    const int half = t >> 8;
    const int lt   = t & 255;
    int* deg   = (int*)(ws + (half ? OFF_DEG2   : OFF_DEG));
    int* start = (int*)(ws + (half ? OFF_START2 : OFF_START));
    int* curs  = (int*)(ws + (half ? OFF_CURS2  : OFF_CURS));
    const int base = lt * 40;
    int s = 0;
    for (int k = 0; k < 40; ++k) {
        int idx = base + k;
        if (idx < N_CNT) s += deg[idx];
    }
    ssum[t] = s;
    __syncthreads();
    for (int off = 1; off < 256; off <<= 1) {
        int v = (lt >= off) ? ssum[t - off] : 0;
        __syncthreads();
        ssum[t] += v;
        __syncthreads();
    }
    int run = ssum[t] - s;
    for (int k = 0; k < 40; ++k) {
        int idx = base + k;
        if (idx < N_CNT) {
            start[idx] = run;
            curs[idx]  = run;
            run += deg[idx];
        }
    }
    if (lt == 255) start[N_CNT] = E_CNT;
    __syncthreads();                                   /* all deg reads done */
    for (int k = t; k < N_CNT; k += 512) ws[OFF_Z + k] = 0.f;   /* Z aliases DEG */
}

// ---------------- fill: src-CSR + dst-position per src-slot ----------------
__global__ __launch_bounds__(256) void fill_kernel(const int* __restrict__ ei, float* __restrict__ ws)
{
    const int e = blockIdx.x * 256 + threadIdx.x;      /* 625*256 = 160000 exact */
    int pd = atomicAdd((int*)(ws + OFF_CURS)  + ei[E_CNT + e], 1);
    int ps = atomicAdd((int*)(ws + OFF_CURS2) + ei[e], 1);
    ((int*)(ws + OFF_ELIST2))[ps] = e;
    ((int*)(ws + OFF_DPOS))[ps]   = pd;
}

// ---------------- edge-kernel helpers ----------------
/* plane-strided load: 12 uint4 at stride 10000 uint4 (160 KB) */
static __device__ __forceinline__ void load48p(unsigned (&ub)[48], const uint4* __restrict__ p0)
{
#pragma unroll
    for (int q = 0; q < 12; ++q) {
        uint4 v = p0[(size_t)q * 10000];
        ub[4 * q + 0] = v.x; ub[4 * q + 1] = v.y;
        ub[4 * q + 2] = v.z; ub[4 * q + 3] = v.w;
    }
}

/* pair-converted accumulate (R15): one __bfloat1622float2 per u32 instead of 2 bit-twiddles */
static __device__ __forceinline__ void accum48(const unsigned (&ub)[48], float hc, float sh0,
    float s1x, float s1y, float s1z,
    float (&o0)[16], float (&o1)[24], float (&t2a)[8])
{
    const float hs = hc * sh0;
#pragma unroll
    for (int j = 0; j < 8; ++j) {
        float2 g = bfp(ub[j]);
        o0[2 * j]     = fmaf(hs, g.x, o0[2 * j]);
        o0[2 * j + 1] = fmaf(hs, g.y, o0[2 * j + 1]);
    }
#pragma unroll
    for (int j = 0; j < 4; ++j) {
        float2 g = bfp(ub[8 + j]);
        t2a[2 * j]     = fmaf(hc, g.x, t2a[2 * j]);
        t2a[2 * j + 1] = fmaf(hc, g.y, t2a[2 * j + 1]);
    }
#pragma unroll
    for (int j = 0; j < 12; ++j) {
        float2 g = bfp(ub[12 + j]);
        o1[2 * j]     = fmaf(hs, g.x, o1[2 * j]);
        o1[2 * j + 1] = fmaf(hs, g.y, o1[2 * j + 1]);
    }
    float g4[48];
#pragma unroll
    for (int j = 0; j < 24; ++j) {
        float2 g = bfp(ub[24 + j]);
        g4[2 * j] = g.x; g4[2 * j + 1] = g.y;
    }
#pragma unroll
    for (int w = 0; w < 16; ++w) {
        float g = g4[3 * w] * s1x;
        g = fmaf(g4[3 * w + 1], s1y, g);
        g = fmaf(g4[3 * w + 2], s1z, g);
        o0[w] = fmaf(hc, g, o0[w]);
    }
}

// ---------------- per-edge main kernel: R12/R14 winner + pair-cvt + bf16 V store ----------------
__global__ __launch_bounds__(128, 2) void edge_kernel(
    const int* __restrict__ ei, float* __restrict__ ws)
{
    const int tid  = threadIdx.x;
    const int pass = tid >> 6;          /* wave 0: K, wave 1: V */
    const int lane = tid & 63;
    /* XCD swizzle: give each XCD a contiguous src range (2496 = 8*312) */
    const int b  = blockIdx.x;
    const int lb = (b < 2496) ? ((b & 7) * 312 + (b >> 3)) : b;
    const int sidx = lb * 64 + lane;    /* src-sorted edge index; 2500*64 = 160000 exact */
    const int e    = ((const int*)(ws + OFF_ELIST2))[sidx];
    const int dpos = ((const int*)(ws + OFF_DPOS))[sidx];
    const int src  = ei[e];
    const int dst  = ei[E_CNT + e];

    /* plane-layout base for this (src, pass) */
    const uint4* gb = (const uint4*)(ws + OFF_G) + (size_t)pass * 1920000 + src;
    unsigned A[48], B[48];
    load48p(A, gb);
    load48p(B, gb + 120000);

    const float d   = ws[OFF_AMFF + e];
    const float dsv = d * INV_STEP;
    float emb[16];
#pragma unroll
    for (int bb = 0; bb < 16; ++bb) {
        float t1 = dsv - (float)bb;
        float t2 = (float)(bb + 2) - dsv;
        float v = 0.f;
        if (t1 > 0.f && t2 > 0.f) v = EMB_C * expf(-1.f / t1 - 1.f / t2);
        emb[bb] = v;
    }

    const float* W1 = ws + (pass ? OFF_WV1F : OFF_WK1F);
    float h[16];
#pragma unroll
    for (int j = 0; j < 16; ++j) {
        float s = 0.f;
#pragma unroll
        for (int bb = 0; bb < 16; ++bb) s = fmaf(emb[bb], W1[bb * 16 + j], s);
        s *= 0.25f;
        h[j] = s / (1.f + expf(-s));
    }

    const float4 eav = ((const float4*)(ws + OFF_EAF))[e];
    const float sh0 = eav.x, s1x = eav.y, s1y = eav.z, s1z = eav.w;

    float o0[16], o1[24], t2a[8];
#pragma unroll
    for (int i = 0; i < 16; ++i) o0[i] = 0.f;
#pragma unroll
    for (int i = 0; i < 24; ++i) o1[i] = 0.f;
#pragma unroll
    for (int i = 0; i < 8; ++i) t2a[i] = 0.f;

#pragma unroll
    for (int c = 0; c < 16; c += 2) {
        accum48(A, h[c], sh0, s1x, s1y, s1z, o0, o1, t2a);
        if (c + 2 < 16) load48p(A, gb + (size_t)(c + 2) * 120000);
        accum48(B, h[c + 1], sh0, s1x, s1y, s1z, o0, o1, t2a);
        if (c + 3 < 16) load48p(B, gb + (size_t)(c + 3) * 120000);
    }

#pragma unroll
    for (int w = 0; w < 8; ++w) {
        o1[w * 3 + 0] = fmaf(t2a[w], s1x, o1[w * 3 + 0]);
        o1[w * 3 + 1] = fmaf(t2a[w], s1y, o1[w * 3 + 1]);
        o1[w * 3 + 2] = fmaf(t2a[w], s1z, o1[w * 3 + 2]);
    }

    if (pass == 0) {
        const float* pd = ws + OFF_P + dst * 40;
        float sc = 0.f;
#pragma unroll
        for (int j = 0; j < 16; ++j) sc = fmaf(o0[j], pd[j], sc);
#pragma unroll
        for (int j = 0; j < 24; ++j) sc = fmaf(o1[j], pd[16 + j], sc);
        sc = fminf(fmaxf(sc * KSCALE, -60.f), 60.f);
        float ct = 10.f * (1.f - d * 0.125f);
        float cutoff = (ct > 0.f) ? expf(-1.f / ct) : 0.f;
        float ev = fmaxf(cutoff * expf(sc), 0.f);
        ws[OFF_EXPV + dpos] = ev;                      /* dst-sorted slot */
        atomicAdd(ws + OFF_Z + dst, ev);
    } else {
        /* bf16 V store: 40 values -> 20 u32 -> 5 uint4 */
        float vo[40];
#pragma unroll
        for (int j = 0; j < 16; ++j) vo[j] = sanitize(o0[j] * KSCALE);
#pragma unroll
        for (int j = 0; j < 24; ++j) vo[16 + j] = sanitize(o1[j] * KSCALE);
        uint4 pk[5];
        unsigned* pu = (unsigned*)pk;
#pragma unroll
        for (int k = 0; k < 20; ++k)
            pu[k] = (unsigned)f2bf(vo[2 * k]) | ((unsigned)f2bf(vo[2 * k + 1]) << 16);
        uint4* vr = (uint4*)((unsigned short*)(ws + OFF_VBUF) + (size_t)dpos * 40);
#pragma unroll
        for (int q = 0; q < 5; ++q) vr[q] = pk[q];
    }
}

// ---------------- gather: one thread per (node, feature-quad); bf16 VBUF streaming ----------------
__global__ __launch_bounds__(256) void gather_kernel(
    const float* __restrict__ ws, void* __restrict__ out)
{
    const int i = blockIdx.x * 256 + threadIdx.x;
    if (i >= N_CNT * 10) return;
    const int n = i / 10;
    const int q = i - n * 10;
    const int* start = (const int*)(ws + OFF_START);
    const float* expv = ws + OFF_EXPV;
    const unsigned* Vb = (const unsigned*)(ws + OFF_VBUF);   /* bf16 pairs */
    const int s = start[n], t = start[n + 1];

    float zz = ws[OFF_Z + n];
    const float rz = (zz > 0.f) ? 1.f / zz : 1.f;

    float ax = 0.f, ay = 0.f, az = 0.f, aw = 0.f;
    for (int j = s; j < t; ++j) {
        const float we = sqrtf(fmaxf(expv[j] * rz, 0.f));
        uint2 u = *(const uint2*)(Vb + (size_t)j * 20 + 2 * q);   /* elements 4q..4q+3 */
        float2 v0 = bfp(u.x), v1 = bfp(u.y);
        ax = fmaf(we, v0.x, ax); ay = fmaf(we, v0.y, ay);
        az = fmaf(we, v1.x, az); aw = fmaf(we, v1.y, aw);
    }
    ax = sanitize(ax); ay = sanitize(ay); az = sanitize(az); aw = sanitize(aw);
    const int f32 = *(const int*)ws;
    if (f32) {
        float4 o; o.x = ax; o.y = ay; o.z = az; o.w = aw;
        ((float4*)out)[(size_t)n * 10 + q] = o;
    } else {
        uint2 o;
        o.x = (unsigned)f2bf(ax) | ((unsigned)f2bf(ay) << 16);
        o.y = (unsigned)f2bf(az) | ((unsigned)f2bf(aw) << 16);
        ((uint2*)out)[(size_t)n * 10 + q] = o;
    }
}

extern "C" void kernel_launch(void* const* d_in, const int* in_sizes, int n_in,
                              void* d_out, int out_size, void* d_ws, size_t ws_size,
                              hipStream_t stream)
{
    (void)in_sizes; (void)n_in; (void)out_size; (void)ws_size;
    const void* x   = d_in[0];
    const int*  ei  = (const int*)d_in[1];
    const void* ea  = d_in[2];
    const void* amf = d_in[5];
    const void* Wq0 = d_in[6];
    const void* Wq1 = d_in[7];
    const void* Wk1 = d_in[8];
    const void* Wk2 = d_in[9];
    const void* Wv1 = d_in[10];
    const void* Wv2 = d_in[11];
    const void* Wd0 = d_in[12];
    const void* Wd1 = d_in[13];

    float* ws = (float*)d_ws;

    hipMemsetAsync(ws + OFF_DEG, 0, 20000 * sizeof(int), stream);   /* DEG + DEG2 adjacent */
    detect_kernel<<<1, 64, 0, stream>>>((const unsigned short*)x, (int*)ws);
    prep_kernel<<<625, 256, 0, stream>>>(ea, amf, Wk1, Wv1, ei, ws);
    gp_kernel<<<1290, 256, 0, stream>>>(x, Wq0, Wq1, Wk2, Wv2, Wd0, Wd1, ws);
    scan_kernel<<<1, 512, 0, stream>>>(ws);
    fill_kernel<<<625, 256, 0, stream>>>(ei, ws);
    edge_kernel<<<2500, 128, 0, stream>>>(ei, ws);
    gather_kernel<<<(N_CNT * 10 + 255) / 256, 256, 0, stream>>>(ws, d_out);
}

// Round 16
// 281.937 us; speedup vs baseline: 1.0690x; 1.0059x over previous
//
#include <hip/hip_runtime.h>
#include <hip/hip_bf16.h>

#define E_CNT 160000
#define N_CNT 10000

#define INV_STEP   2.125f          /* 17/8 */
#define EMB_C      33.734292f      /* 1.14136 * e^2 * sqrt(16) */
#define INVS320    0.05590170f     /* 1/sqrt(320) */
#define INVS8      0.35355339f     /* 1/sqrt(8)   */
#define INV_SQRT3  0.57735027f
#define KSCALE     0.051031036f    /* 0.25 (w/sqrt16) * 1/sqrt(24) (fctp norm) */

/* ---- workspace layout (float-sized offsets) ---- */
#define OFF_FLAG   0          /* 16 floats reserved (int flag at [0]) */
#define OFF_EAF    400016     /* 640000 */
#define OFF_AMFF   1040016    /* 160000 */
#define OFF_WK1F   1200656    /* 256 */
#define OFF_WV1F   1200912    /* 256 */
#define OFF_P      1219600    /* 400000 */
#define OFF_EXPV   1619600    /* 160000 (dst-sorted order, fp32) */
#define OFF_VBUF   1779600    /* E*40 bf16 = 12.8 MB (dst-sorted order) */
#define OFF_DEG    8179600    /* 10000 ints (dst); reused as Z (zeroed at end of scan) */
#define OFF_Z      8179600    /* alias of OFF_DEG */
#define OFF_DEG2   8189600    /* 10000 ints (src) -- adjacent to DEG: single memset */
#define OFF_START  8199600    /* 10001 ints */
#define OFF_START2 8209601    /* 10001 ints */
#define OFF_CURS   8219602    /* 10000 ints */
#define OFF_CURS2  8229602    /* 10000 ints */
#define OFF_DPOS   8239602    /* 160000 ints: dst-position of edge at src-sorted slot */
#define OFF_ELIST2 8399602    /* 160000 ints */
#define OFF_G      8559632    /* G planes: 32*12*10000 uint4 = 61.44 MB */
/* total 23,919,632 floats = 95.7 MB (same extent as R5-R15 -- verified mapped) */

/* G plane layout: element (n, p, c, q) at uint4 index p*1920000 + c*120000 + q*10000 + n */

static __device__ __forceinline__ float bf2f(__hip_bfloat16 b) { return __bfloat162float(b); }
static __device__ __forceinline__ float sanitize(float v) {
    return fminf(fmaxf(v, -1e30f), 1e30f);
}
static __device__ __forceinline__ unsigned short f2bf(float f) {
    unsigned x = __float_as_uint(f);
    unsigned r = (x + 0x7fffu + ((x >> 16) & 1u)) >> 16;   /* RN-even */
    return (unsigned short)r;
}
static __device__ __forceinline__ float bflo(unsigned u) { return __uint_as_float(u << 16); }
static __device__ __forceinline__ float bfhi(unsigned u) { return __uint_as_float(u & 0xffff0000u); }
/* pair convert kept ONLY for gather (once per element there; R15 proved it hurts in edge's hot loop) */
static __device__ __forceinline__ float2 bfp(unsigned u) {
    float2 r; r.x = bflo(u); r.y = bfhi(u); return r;
}

/* load 4 consecutive floats from a maybe-bf16 / maybe-f32 buffer at element quad index i4 */
static __device__ __forceinline__ float4 load4(const void* p, int i4, int f32)
{
    if (f32) return ((const float4*)p)[i4];
    uint2 u = ((const uint2*)p)[i4];
    float4 r;
    r.x = bflo(u.x); r.y = bfhi(u.x);
    r.z = bflo(u.y); r.w = bfhi(u.y);
    return r;
}

/* 8-wide vector load: bf16 = one uint4 (16 B), f32 = two float4. p must be 16B-aligned. */
static __device__ __forceinline__ void ld8(const float* p, float (&r)[8])
{
    float4 a = ((const float4*)p)[0];
    float4 b = ((const float4*)p)[1];
    r[0] = a.x; r[1] = a.y; r[2] = a.z; r[3] = a.w;
    r[4] = b.x; r[5] = b.y; r[6] = b.z; r[7] = b.w;
}
static __device__ __forceinline__ void ld8(const __hip_bfloat16* p, float (&r)[8])
{
    uint4 u = *(const uint4*)p;
    r[0] = bflo(u.x); r[1] = bfhi(u.x); r[2] = bflo(u.y); r[3] = bfhi(u.y);
    r[4] = bflo(u.z); r[5] = bfhi(u.z); r[6] = bflo(u.w); r[7] = bfhi(u.w);
}

// ---------------- detect: ONCE, 64 threads, shfl-reduce ----------------
__global__ void detect_kernel(const unsigned short* __restrict__ xb, int* __restrict__ flag)
{
    const int lane = threadIdx.x;                     /* 64 threads */
    unsigned e0 = (unsigned)((xb[2 * lane] >> 7) & 0xFF);        /* even u16 = fp32 low halves */
    unsigned e1 = (unsigned)((xb[128 + 2 * lane] >> 7) & 0xFF);
    int c = (e0 >= 141 ? 1 : 0) + (e1 >= 141 ? 1 : 0);
#pragma unroll
    for (int off = 1; off < 64; off <<= 1) c += __shfl_xor(c, off);
    if (lane == 0) *flag = (c >= 8) ? 1 : 0;          /* 1 = inputs are fp32 */
}

// ---------------- prep: ingest EA/AMF/W1 + degree atomics ----------------
__global__ __launch_bounds__(256) void prep_kernel(
    const void* __restrict__ ea, const void* __restrict__ amf,
    const void* __restrict__ Wk1, const void* __restrict__ Wv1,
    const int* __restrict__ ei, float* __restrict__ ws)
{
    const int f32 = *(const int*)ws;
    const int i = blockIdx.x * 256 + threadIdx.x;     /* 625 blocks -> 160000 threads */
    if (i < 160000) ((float4*)(ws + OFF_EAF))[i] = load4(ea, i, f32);
    if (i < 40000) {
        ((float4*)(ws + OFF_AMFF))[i] = load4(amf, i, f32);
#pragma unroll
        for (int k = 0; k < 4; ++k) {
            atomicAdd((int*)(ws + OFF_DEG)  + ei[E_CNT + 4 * i + k], 1);   /* dst degree */
            atomicAdd((int*)(ws + OFF_DEG2) + ei[4 * i + k], 1);           /* src degree */
        }
    }
    if (i < 64) {
        ((float4*)(ws + OFF_WK1F))[i] = load4(Wk1, i, f32);
        ((float4*)(ws + OFF_WV1F))[i] = load4(Wv1, i, f32);
    }
}

// ---------------- G builder: vectorized loads, plane-transposed coalesced stores ----------------
template <typename T>
static __device__ __forceinline__ void build_G(
    const T* __restrict__ x, const T* __restrict__ W2b, int n, int p, int c, float* __restrict__ ws)
{
    float xs[40];
#pragma unroll
    for (int q = 0; q < 5; ++q) ld8(x + n * 40 + q * 8, *(float(*)[8])(xs + q * 8));
    const T* W2 = W2b + c * 576;

    float out[96];
#pragma unroll
    for (int k = 0; k < 96; ++k) out[k] = 0.f;

    /* seg1 */
#pragma unroll
    for (int u = 0; u < 16; ++u) {
        float r0[8], r1[8];
        ld8(W2 + u * 16, r0);
        ld8(W2 + u * 16 + 8, r1);
        const float xv = xs[u];
#pragma unroll
        for (int w = 0; w < 8; ++w) {
            out[w]     = fmaf(r0[w], xv, out[w]);
            out[8 + w] = fmaf(r1[w], xv, out[8 + w]);
        }
    }
    /* seg2 */
#pragma unroll
    for (int u = 0; u < 16; ++u) {
        float r[8];
        ld8(W2 + 256 + u * 8, r);
        const float xv = xs[u];
#pragma unroll
        for (int w = 0; w < 8; ++w) out[16 + w] = fmaf(r[w], xv, out[16 + w]);
    }
    /* seg3 */
#pragma unroll
    for (int u = 0; u < 8; ++u) {
        float r[8];
        ld8(W2 + 384 + u * 8, r);
        const float a0 = xs[16 + u * 3 + 0];
        const float a1 = xs[16 + u * 3 + 1];
        const float a2 = xs[16 + u * 3 + 2];
#pragma unroll
        for (int w = 0; w < 8; ++w) {
            out[24 + w * 3 + 0] = fmaf(r[w], a0, out[24 + w * 3 + 0]);
            out[24 + w * 3 + 1] = fmaf(r[w], a1, out[24 + w * 3 + 1]);
            out[24 + w * 3 + 2] = fmaf(r[w], a2, out[24 + w * 3 + 2]);
        }
    }
    /* seg4 (scaled by 1/sqrt3 below) */
#pragma unroll
    for (int u = 0; u < 8; ++u) {
        float r0[8], r1[8];
        ld8(W2 + 448 + u * 16, r0);
        ld8(W2 + 448 + u * 16 + 8, r1);
        const float a0 = xs[16 + u * 3 + 0];
        const float a1 = xs[16 + u * 3 + 1];
        const float a2 = xs[16 + u * 3 + 2];
#pragma unroll
        for (int w = 0; w < 8; ++w) {
            out[48 + w * 3 + 0] = fmaf(r0[w], a0, out[48 + w * 3 + 0]);
            out[48 + w * 3 + 1] = fmaf(r0[w], a1, out[48 + w * 3 + 1]);
            out[48 + w * 3 + 2] = fmaf(r0[w], a2, out[48 + w * 3 + 2]);
            out[48 + (8 + w) * 3 + 0] = fmaf(r1[w], a0, out[48 + (8 + w) * 3 + 0]);
            out[48 + (8 + w) * 3 + 1] = fmaf(r1[w], a1, out[48 + (8 + w) * 3 + 1]);
            out[48 + (8 + w) * 3 + 2] = fmaf(r1[w], a2, out[48 + (8 + w) * 3 + 2]);
        }
    }
#pragma unroll
    for (int k = 0; k < 48; ++k) out[48 + k] *= INV_SQRT3;

    uint4 ov[12];
    unsigned* ou = (unsigned*)ov;
#pragma unroll
    for (int k = 0; k < 48; ++k)
        ou[k] = (unsigned)f2bf(out[2 * k]) | ((unsigned)f2bf(out[2 * k + 1]) << 16);
    uint4* gb = (uint4*)(ws + OFF_G) + (size_t)(p * 16 + c) * 120000 + n;
#pragma unroll
    for (int q = 0; q < 12; ++q) gb[q * 10000] = ov[q];
}

// ---------------- P builder (vectorized loads) ----------------
template <typename T>
static __device__ __forceinline__ void build_P(
    const T* __restrict__ x, const T* __restrict__ Wq0, const T* __restrict__ Wq1,
    const T* __restrict__ Wd0, const T* __restrict__ Wd1, int n, float* __restrict__ ws)
{
    float xs[40];
#pragma unroll
    for (int q = 0; q < 5; ++q) ld8(x + n * 40 + q * 8, *(float(*)[8])(xs + q * 8));

    float q0[16];
#pragma unroll
    for (int w = 0; w < 16; ++w) q0[w] = 0.f;
#pragma unroll
    for (int u = 0; u < 16; ++u) {
        float r0[8], r1[8];
        ld8(Wq0 + u * 16, r0);
        ld8(Wq0 + u * 16 + 8, r1);
        const float xv = xs[u];
#pragma unroll
        for (int w = 0; w < 8; ++w) {
            q0[w]     = fmaf(r0[w], xv, q0[w]);
            q0[8 + w] = fmaf(r1[w], xv, q0[8 + w]);
        }
    }
#pragma unroll
    for (int w = 0; w < 16; ++w) q0[w] *= 0.25f;

    float p0[16];
#pragma unroll
    for (int v = 0; v < 16; ++v) p0[v] = 0.f;
#pragma unroll
    for (int w = 0; w < 16; ++w) {
        float r0[8], r1[8];
        ld8(Wd0 + w * 16, r0);
        ld8(Wd0 + w * 16 + 8, r1);
        const float qv = q0[w];
#pragma unroll
        for (int v = 0; v < 8; ++v) {
            p0[v]     = fmaf(r0[v], qv, p0[v]);
            p0[8 + v] = fmaf(r1[v], qv, p0[8 + v]);
        }
    }
    float* pn = ws + OFF_P + n * 40;
#pragma unroll
    for (int v = 0; v < 16; ++v) pn[v] = sanitize(p0[v] * INVS320);

    float q1[24];
#pragma unroll
    for (int k = 0; k < 24; ++k) q1[k] = 0.f;
#pragma unroll
    for (int u = 0; u < 8; ++u) {
        float r[8];
        ld8(Wq1 + u * 8, r);
        const float a0 = xs[16 + u * 3 + 0];
        const float a1 = xs[16 + u * 3 + 1];
        const float a2 = xs[16 + u * 3 + 2];
#pragma unroll
        for (int w = 0; w < 8; ++w) {
            q1[w * 3 + 0] = fmaf(r[w], a0, q1[w * 3 + 0]);
            q1[w * 3 + 1] = fmaf(r[w], a1, q1[w * 3 + 1]);
            q1[w * 3 + 2] = fmaf(r[w], a2, q1[w * 3 + 2]);
        }
    }
#pragma unroll
    for (int k = 0; k < 24; ++k) q1[k] *= INVS8;

    float p1[24];
#pragma unroll
    for (int k = 0; k < 24; ++k) p1[k] = 0.f;
#pragma unroll
    for (int w = 0; w < 8; ++w) {
        float r[8];
        ld8(Wd1 + w * 8, r);
        const float b0 = q1[w * 3 + 0];
        const float b1 = q1[w * 3 + 1];
        const float b2 = q1[w * 3 + 2];
#pragma unroll
        for (int v = 0; v < 8; ++v) {
            p1[v * 3 + 0] = fmaf(r[v], b0, p1[v * 3 + 0]);
            p1[v * 3 + 1] = fmaf(r[v], b1, p1[v * 3 + 1]);
            p1[v * 3 + 2] = fmaf(r[v], b2, p1[v * 3 + 2]);
        }
    }
    const float sc = INVS320 * INV_SQRT3;
#pragma unroll
    for (int k = 0; k < 24; ++k) pn[16 + k] = sanitize(p1[k] * sc);
}

// ---------------- gp: [0,1250) G | [1250,1290) P ----------------
__global__ __launch_bounds__(256) void gp_kernel(
    const void* __restrict__ x,
    const void* __restrict__ Wq0, const void* __restrict__ Wq1,
    const void* __restrict__ Wk2, const void* __restrict__ Wv2,
    const void* __restrict__ Wd0, const void* __restrict__ Wd1,
    float* __restrict__ ws)
{
    const int f32 = *(const int*)ws;
    const int tid = threadIdx.x;
    const int blk = blockIdx.x;
    if (blk < 1250) {
        const int t = blk * 256 + tid;               /* < 320000 */
        const int p   = t / 160000;
        const int rem = t - p * 160000;
        const int c   = rem / 10000;
        const int n   = rem - c * 10000;
        const void* W2b = p ? Wv2 : Wk2;
        if (f32) build_G((const float*)x, (const float*)W2b, n, p, c, ws);
        else     build_G((const __hip_bfloat16*)x, (const __hip_bfloat16*)W2b, n, p, c, ws);
        return;
    }
    {
        const int n = (blk - 1250) * 256 + tid;
        if (n >= N_CNT) return;
        if (f32) build_P((const float*)x, (const float*)Wq0, (const float*)Wq1,
                         (const float*)Wd0, (const float*)Wd1, n, ws);
        else     build_P((const __hip_bfloat16*)x, (const __hip_bfloat16*)Wq0,
                         (const __hip_bfloat16*)Wq1, (const __hip_bfloat16*)Wd0,
                         (const __hip_bfloat16*)Wd1, n, ws);
    }
}

// ---------------- dual scan (512 threads: half dst, half src) + zero Z at end ----------------
__global__ __launch_bounds__(512) void scan_kernel(float* __restrict__ ws)
{
    __shared__ int ssum[512];
    const int t    = threadIdx.x;
    const int half = t >> 8;
    const int lt   = t & 255;
    int* deg   = (int*)(ws + (half ? OFF_DEG2   : OFF_DEG));
    int* start = (int*)(ws + (half ? OFF_START2 : OFF_START));
    int* curs  = (int*)(ws + (half ? OFF_CURS2  : OFF_CURS));
    const int base = lt * 40;
    int s = 0;
    for (int k = 0; k < 40; ++k) {
        int idx = base + k;
        if (idx < N_CNT) s += deg[idx];
    }
    ssum[t] = s;
    __syncthreads();
    for (int off = 1; off < 256; off <<= 1) {
        int v = (lt >= off) ? ssum[t - off] : 0;
        __syncthreads();
        ssum[t] += v;
        __syncthreads();
    }
    int run = ssum[t] - s;
    for (int k = 0; k < 40; ++k) {
        int idx = base + k;
        if (idx < N_CNT) {
            start[idx] = run;
            curs[idx]  = run;
            run += deg[idx];
        }
    }
    if (lt == 255) start[N_CNT] = E_CNT;
    __syncthreads();                                   /* all deg reads done */
    for (int k = t; k < N_CNT; k += 512) ws[OFF_Z + k] = 0.f;   /* Z aliases DEG */
}

// ---------------- fill: src-CSR + dst-position per src-slot ----------------
__global__ __launch_bounds__(256) void fill_kernel(const int* __restrict__ ei, float* __restrict__ ws)
{
    const int e = blockIdx.x * 256 + threadIdx.x;      /* 625*256 = 160000 exact */
    int pd = atomicAdd((int*)(ws + OFF_CURS)  + ei[E_CNT + e], 1);
    int ps = atomicAdd((int*)(ws + OFF_CURS2) + ei[e], 1);
    ((int*)(ws + OFF_ELIST2))[ps] = e;
    ((int*)(ws + OFF_DPOS))[ps]   = pd;
}

// ---------------- edge-kernel helpers ----------------
/* plane-strided load: 12 uint4 at stride 10000 uint4 (160 KB) */
static __device__ __forceinline__ void load48p(unsigned (&ub)[48], const uint4* __restrict__ p0)
{
#pragma unroll
    for (int q = 0; q < 12; ++q) {
        uint4 v = p0[(size_t)q * 10000];
        ub[4 * q + 0] = v.x; ub[4 * q + 1] = v.y;
        ub[4 * q + 2] = v.z; ub[4 * q + 3] = v.w;
    }
}

/* R14-proven bit-twiddle accumulate: strict FIFO consumption, no temp arrays.
   R15 proved __bfloat1622float2 + staging array here costs ~40 us -- do not reintroduce. */
static __device__ __forceinline__ void accum48(const unsigned (&ub)[48], float hc, float sh0,
    float s1x, float s1y, float s1z,
    float (&o0)[16], float (&o1)[24], float (&t2a)[8])
{
    const float hs = hc * sh0;
#define GVAL(k) (((k) & 1) ? bfhi(ub[(k) >> 1]) : bflo(ub[(k) >> 1]))
#pragma unroll
    for (int w = 0; w < 16; ++w) o0[w] = fmaf(hs, GVAL(w), o0[w]);
#pragma unroll
    for (int w = 0; w < 8; ++w) t2a[w] = fmaf(hc, GVAL(16 + w), t2a[w]);
#pragma unroll
    for (int k = 0; k < 24; ++k) o1[k] = fmaf(hs, GVAL(24 + k), o1[k]);
#pragma unroll
    for (int w = 0; w < 16; ++w) {
        float g = GVAL(48 + w * 3 + 0) * s1x;
        g = fmaf(GVAL(48 + w * 3 + 1), s1y, g);
        g = fmaf(GVAL(48 + w * 3 + 2), s1z, g);
        o0[w] = fmaf(hc, g, o0[w]);
    }
#undef GVAL
}

// ---------------- per-edge main kernel: R14 accum + plane reads + bf16 V store ----------------
__global__ __launch_bounds__(128, 2) void edge_kernel(
    const int* __restrict__ ei, float* __restrict__ ws)
{
    const int tid  = threadIdx.x;
    const int pass = tid >> 6;          /* wave 0: K, wave 1: V */
    const int lane = tid & 63;
    /* XCD swizzle: give each XCD a contiguous src range (2496 = 8*312) */
    const int b  = blockIdx.x;
    const int lb = (b < 2496) ? ((b & 7) * 312 + (b >> 3)) : b;
    const int sidx = lb * 64 + lane;    /* src-sorted edge index; 2500*64 = 160000 exact */
    const int e    = ((const int*)(ws + OFF_ELIST2))[sidx];
    const int dpos = ((const int*)(ws + OFF_DPOS))[sidx];
    const int src  = ei[e];
    const int dst  = ei[E_CNT + e];

    /* plane-layout base for this (src, pass) */
    const uint4* gb = (const uint4*)(ws + OFF_G) + (size_t)pass * 1920000 + src;
    unsigned A[48], B[48];
    load48p(A, gb);
    load48p(B, gb + 120000);

    const float d   = ws[OFF_AMFF + e];
    const float dsv = d * INV_STEP;
    float emb[16];
#pragma unroll
    for (int bb = 0; bb < 16; ++bb) {
        float t1 = dsv - (float)bb;
        float t2 = (float)(bb + 2) - dsv;
        float v = 0.f;
        if (t1 > 0.f && t2 > 0.f) v = EMB_C * expf(-1.f / t1 - 1.f / t2);
        emb[bb] = v;
    }

    const float* W1 = ws + (pass ? OFF_WV1F : OFF_WK1F);
    float h[16];
#pragma unroll
    for (int j = 0; j < 16; ++j) {
        float s = 0.f;
#pragma unroll
        for (int bb = 0; bb < 16; ++bb) s = fmaf(emb[bb], W1[bb * 16 + j], s);
        s *= 0.25f;
        h[j] = s / (1.f + expf(-s));
    }

    const float4 eav = ((const float4*)(ws + OFF_EAF))[e];
    const float sh0 = eav.x, s1x = eav.y, s1y = eav.z, s1z = eav.w;

    float o0[16], o1[24], t2a[8];
#pragma unroll
    for (int i = 0; i < 16; ++i) o0[i] = 0.f;
#pragma unroll
    for (int i = 0; i < 24; ++i) o1[i] = 0.f;
#pragma unroll
    for (int i = 0; i < 8; ++i) t2a[i] = 0.f;

#pragma unroll
    for (int c = 0; c < 16; c += 2) {
        accum48(A, h[c], sh0, s1x, s1y, s1z, o0, o1, t2a);
        if (c + 2 < 16) load48p(A, gb + (size_t)(c + 2) * 120000);
        accum48(B, h[c + 1], sh0, s1x, s1y, s1z, o0, o1, t2a);
        if (c + 3 < 16) load48p(B, gb + (size_t)(c + 3) * 120000);
    }

#pragma unroll
    for (int w = 0; w < 8; ++w) {
        o1[w * 3 + 0] = fmaf(t2a[w], s1x, o1[w * 3 + 0]);
        o1[w * 3 + 1] = fmaf(t2a[w], s1y, o1[w * 3 + 1]);
        o1[w * 3 + 2] = fmaf(t2a[w], s1z, o1[w * 3 + 2]);
    }

    if (pass == 0) {
        const float* pd = ws + OFF_P + dst * 40;
        float sc = 0.f;
#pragma unroll
        for (int j = 0; j < 16; ++j) sc = fmaf(o0[j], pd[j], sc);
#pragma unroll
        for (int j = 0; j < 24; ++j) sc = fmaf(o1[j], pd[16 + j], sc);
        sc = fminf(fmaxf(sc * KSCALE, -60.f), 60.f);
        float ct = 10.f * (1.f - d * 0.125f);
        float cutoff = (ct > 0.f) ? expf(-1.f / ct) : 0.f;
        float ev = fmaxf(cutoff * expf(sc), 0.f);
        ws[OFF_EXPV + dpos] = ev;                      /* dst-sorted slot */
        atomicAdd(ws + OFF_Z + dst, ev);
    } else {
        /* bf16 V store: 40 values -> 20 u32 -> 5 uint4 (once per thread; WRITE 35->28 MB) */
        float vo[40];
#pragma unroll
        for (int j = 0; j < 16; ++j) vo[j] = sanitize(o0[j] * KSCALE);
#pragma unroll
        for (int j = 0; j < 24; ++j) vo[16 + j] = sanitize(o1[j] * KSCALE);
        uint4 pk[5];
        unsigned* pu = (unsigned*)pk;
#pragma unroll
        for (int k = 0; k < 20; ++k)
            pu[k] = (unsigned)f2bf(vo[2 * k]) | ((unsigned)f2bf(vo[2 * k + 1]) << 16);
        uint4* vr = (uint4*)((unsigned short*)(ws + OFF_VBUF) + (size_t)dpos * 40);
#pragma unroll
        for (int q = 0; q < 5; ++q) vr[q] = pk[q];
    }
}

// ---------------- gather: one thread per (node, feature-quad); bf16 VBUF streaming ----------------
__global__ __launch_bounds__(256) void gather_kernel(
    const float* __restrict__ ws, void* __restrict__ out)
{
    const int i = blockIdx.x * 256 + threadIdx.x;
    if (i >= N_CNT * 10) return;
    const int n = i / 10;
    const int q = i - n * 10;
    const int* start = (const int*)(ws + OFF_START);
    const float* expv = ws + OFF_EXPV;
    const unsigned* Vb = (const unsigned*)(ws + OFF_VBUF);   /* bf16 pairs */
    const int s = start[n], t = start[n + 1];

    float zz = ws[OFF_Z + n];
    const float rz = (zz > 0.f) ? 1.f / zz : 1.f;

    float ax = 0.f, ay = 0.f, az = 0.f, aw = 0.f;
    for (int j = s; j < t; ++j) {
        const float we = sqrtf(fmaxf(expv[j] * rz, 0.f));
        uint2 u = *(const uint2*)(Vb + (size_t)j * 20 + 2 * q);   /* elements 4q..4q+3 */
        float2 v0 = bfp(u.x), v1 = bfp(u.y);
        ax = fmaf(we, v0.x, ax); ay = fmaf(we, v0.y, ay);
        az = fmaf(we, v1.x, az); aw = fmaf(we, v1.y, aw);
    }
    ax = sanitize(ax); ay = sanitize(ay); az = sanitize(az); aw = sanitize(aw);
    const int f32 = *(const int*)ws;
    if (f32) {
        float4 o; o.x = ax; o.y = ay; o.z = az; o.w = aw;
        ((float4*)out)[(size_t)n * 10 + q] = o;
    } else {
        uint2 o;
        o.x = (unsigned)f2bf(ax) | ((unsigned)f2bf(ay) << 16);
        o.y = (unsigned)f2bf(az) | ((unsigned)f2bf(aw) << 16);
        ((uint2*)out)[(size_t)n * 10 + q] = o;
    }
}

extern "C" void kernel_launch(void* const* d_in, const int* in_sizes, int n_in,
                              void* d_out, int out_size, void* d_ws, size_t ws_size,
                              hipStream_t stream)
{
    (void)in_sizes; (void)n_in; (void)out_size; (void)ws_size;
    const void* x   = d_in[0];
    const int*  ei  = (const int*)d_in[1];
    const void* ea  = d_in[2];
    const void* amf = d_in[5];
    const void* Wq0 = d_in[6];
    const void* Wq1 = d_in[7];
    const void* Wk1 = d_in[8];
    const void* Wk2 = d_in[9];
    const void* Wv1 = d_in[10];
    const void* Wv2 = d_in[11];
    const void* Wd0 = d_in[12];
    const void* Wd1 = d_in[13];

    float* ws = (float*)d_ws;

    hipMemsetAsync(ws + OFF_DEG, 0, 20000 * sizeof(int), stream);   /* DEG + DEG2 adjacent */
    detect_kernel<<<1, 64, 0, stream>>>((const unsigned short*)x, (int*)ws);
    prep_kernel<<<625, 256, 0, stream>>>(ea, amf, Wk1, Wv1, ei, ws);
    gp_kernel<<<1290, 256, 0, stream>>>(x, Wq0, Wq1, Wk2, Wv2, Wd0, Wd1, ws);
    scan_kernel<<<1, 512, 0, stream>>>(ws);
    fill_kernel<<<625, 256, 0, stream>>>(ei, ws);
    edge_kernel<<<2500, 128, 0, stream>>>(ei, ws);
    gather_kernel<<<(N_CNT * 10 + 255) / 256, 256, 0, stream>>>(ws, d_out);
}